// Round 6
// baseline (507.339 us; speedup 1.0000x reference)
//
#include <hip/hip_runtime.h>

// Problem constants
#define NROWS 65536   // 64*64*32*32 / 64
#define KC    1024
#define DD    64

// Output layout (floats) in d_out
#define QOFF  0                     // quantized_st: 4194304
#define IOFF  4194304               // indices:        65536
#define WOFF  4259840               // new_weight:     65536
#define CSOFF 4325376               // cs:              1024
#define EAOFF 4326400               // new_embed_avg:  65536

// Workspace layout (floats)
#define WS_CODESQ 0        // 1024 exact ||w_k||^2
#define WS_COUNTS 1024     // 1024
#define WS_DW     2048     // 65536
#define WS_RCCNT  67584    // 16 (int count + pad)
#define WS_CSFIN  67600    // 1024
#define WS_WF16   68624    // 32768 floats = 65536 halves (w*1024 in f16)
#define WS_RCLIST 101392   // 65536 ints

#define MARGIN 1e-3f

typedef _Float16 half8 __attribute__((ext_vector_type(8)));
typedef float    floatx4 __attribute__((ext_vector_type(4)));

// Exact rowsq: numpy pairwise order over float4-held row (same as R5, passing).
__device__ __forceinline__ float rowsq4(const float4* xv) {
    float4 re, ro;
    re.x = __fmul_rn(xv[0].x, xv[0].x); re.y = __fmul_rn(xv[0].y, xv[0].y);
    re.z = __fmul_rn(xv[0].z, xv[0].z); re.w = __fmul_rn(xv[0].w, xv[0].w);
    ro.x = __fmul_rn(xv[1].x, xv[1].x); ro.y = __fmul_rn(xv[1].y, xv[1].y);
    ro.z = __fmul_rn(xv[1].z, xv[1].z); ro.w = __fmul_rn(xv[1].w, xv[1].w);
#pragma unroll
    for (int i = 2; i < 16; i += 2) {
        re.x = __fadd_rn(re.x, __fmul_rn(xv[i].x, xv[i].x));
        re.y = __fadd_rn(re.y, __fmul_rn(xv[i].y, xv[i].y));
        re.z = __fadd_rn(re.z, __fmul_rn(xv[i].z, xv[i].z));
        re.w = __fadd_rn(re.w, __fmul_rn(xv[i].w, xv[i].w));
        ro.x = __fadd_rn(ro.x, __fmul_rn(xv[i + 1].x, xv[i + 1].x));
        ro.y = __fadd_rn(ro.y, __fmul_rn(xv[i + 1].y, xv[i + 1].y));
        ro.z = __fadd_rn(ro.z, __fmul_rn(xv[i + 1].z, xv[i + 1].z));
        ro.w = __fadd_rn(ro.w, __fmul_rn(xv[i + 1].w, xv[i + 1].w));
    }
    return __fadd_rn(__fadd_rn(__fadd_rn(re.x, re.y), __fadd_rn(re.z, re.w)),
                     __fadd_rn(__fadd_rn(ro.x, ro.y), __fadd_rn(ro.z, ro.w)));
}

// ---- Kernel A: exact code_sq + f16(1024*w) codebook ----
__global__ void prep_kernel(const float* __restrict__ weight,
                            float* __restrict__ code_sq,
                            _Float16* __restrict__ wf16) {
    int c = blockIdx.x * blockDim.x + threadIdx.x;
    if (c >= KC) return;
    float4 wv4[16];
    const float4* pw = reinterpret_cast<const float4*>(weight + (size_t)c * DD);
#pragma unroll
    for (int i = 0; i < 16; ++i) wv4[i] = pw[i];
    code_sq[c] = rowsq4(wv4);
#pragma unroll
    for (int gqi = 0; gqi < 8; ++gqi) {
        half8 hh;
        float4 a = wv4[2 * gqi], b = wv4[2 * gqi + 1];
        hh[0] = (_Float16)(a.x * 1024.0f); hh[1] = (_Float16)(a.y * 1024.0f);
        hh[2] = (_Float16)(a.z * 1024.0f); hh[3] = (_Float16)(a.w * 1024.0f);
        hh[4] = (_Float16)(b.x * 1024.0f); hh[5] = (_Float16)(b.y * 1024.0f);
        hh[6] = (_Float16)(b.z * 1024.0f); hh[7] = (_Float16)(b.w * 1024.0f);
        *reinterpret_cast<half8*>(wf16 + (size_t)c * DD + gqi * 8) = hh;
    }
}

// ---- Kernel B: MFMA fast scan + min tracking + decided epilogue ----
// 512 blocks x 256 thr (4 waves). Block = 128 rows; wave = 32 rows (2 M-tiles).
// MFMA 16x16x32 f16: A/B frag lane l: free-dim = l&15, k = (l>>4)*8 + j.
// C frag: col(code) = l&15, row(x-row) = (l>>4)*4 + reg.
__global__ __launch_bounds__(256) void vq_scan(
    const float* __restrict__ x_in, const float* __restrict__ weight,
    const float* __restrict__ code_sq, const _Float16* __restrict__ wf16,
    float* __restrict__ out, float* __restrict__ counts, float* __restrict__ dw,
    int* __restrict__ rccnt, int* __restrict__ rclist) {

    __shared__ int idx_lds[128];

    const int tid  = threadIdx.x;
    const int lane = tid & 63;
    const int wv   = tid >> 6;
    const int l15  = lane & 15;
    const int g    = lane >> 4;

    const int blockRow0 = blockIdx.x * 128;
    const int waveRow0  = blockRow0 + wv * 32;

    // A fragments: x rows, 2 M-tiles x 2 K-halves, converted f32->f16 (RTNE).
    half8 av00, av01, av10, av11;
    {
        const float* p00 = x_in + (size_t)(waveRow0 + l15) * DD + g * 8;
        const float* p01 = p00 + 32;
        const float* p10 = x_in + (size_t)(waveRow0 + 16 + l15) * DD + g * 8;
        const float* p11 = p10 + 32;
#pragma unroll
        for (int j = 0; j < 8; ++j) {
            av00[j] = (_Float16)p00[j];
            av01[j] = (_Float16)p01[j];
            av10[j] = (_Float16)p10[j];
            av11[j] = (_Float16)p11[j];
        }
    }

    float m1_0[4], m2_0[4], m1_1[4], m2_1[4];
    int   i1_0[4], i1_1[4];
#pragma unroll
    for (int r = 0; r < 4; ++r) {
        m1_0[r] = INFINITY; m2_0[r] = INFINITY; i1_0[r] = 0;
        m1_1[r] = INFINITY; m2_1[r] = INFINITY; i1_1[r] = 0;
    }

    for (int ct = 0; ct < 64; ++ct) {
        const int cb = ct * 16;
        const int code = cb + l15;
        half8 b0 = *reinterpret_cast<const half8*>(wf16 + (size_t)code * DD + g * 8);
        half8 b1 = *reinterpret_cast<const half8*>(wf16 + (size_t)code * DD + 32 + g * 8);
        float csq = code_sq[code];

        floatx4 c0 = {0.f, 0.f, 0.f, 0.f};
        c0 = __builtin_amdgcn_mfma_f32_16x16x32_f16(av00, b0, c0, 0, 0, 0);
        c0 = __builtin_amdgcn_mfma_f32_16x16x32_f16(av01, b1, c0, 0, 0, 0);
        floatx4 c1 = {0.f, 0.f, 0.f, 0.f};
        c1 = __builtin_amdgcn_mfma_f32_16x16x32_f16(av10, b0, c1, 0, 0, 0);
        c1 = __builtin_amdgcn_mfma_f32_16x16x32_f16(av11, b1, c1, 0, 0, 0);

#pragma unroll
        for (int r = 0; r < 4; ++r) {
            float s0 = fmaf(c0[r], -0x1p-9f, csq);  // csq - 2*dot/1024
            bool lt0 = s0 < m1_0[r];
            m2_0[r] = lt0 ? m1_0[r] : fminf(m2_0[r], s0);
            i1_0[r] = lt0 ? code : i1_0[r];
            m1_0[r] = lt0 ? s0 : m1_0[r];
            float s1 = fmaf(c1[r], -0x1p-9f, csq);
            bool lt1 = s1 < m1_1[r];
            m2_1[r] = lt1 ? m1_1[r] : fminf(m2_1[r], s1);
            i1_1[r] = lt1 ? code : i1_1[r];
            m1_1[r] = lt1 ? s1 : m1_1[r];
        }
    }

    // Cross-lane argmin reduce within each 16-lane group (butterfly).
#pragma unroll
    for (int r = 0; r < 4; ++r) {
#pragma unroll
        for (int mk = 1; mk < 16; mk <<= 1) {
            {
                float o1 = __shfl_xor(m1_0[r], mk);
                float o2 = __shfl_xor(m2_0[r], mk);
                int   oi = __shfl_xor(i1_0[r], mk);
                float n2 = fminf(fminf(m2_0[r], o2), fmaxf(m1_0[r], o1));
                bool sel = (o1 < m1_0[r]) || (o1 == m1_0[r] && oi < i1_0[r]);
                m1_0[r] = sel ? o1 : m1_0[r];
                i1_0[r] = sel ? oi : i1_0[r];
                m2_0[r] = n2;
            }
            {
                float o1 = __shfl_xor(m1_1[r], mk);
                float o2 = __shfl_xor(m2_1[r], mk);
                int   oi = __shfl_xor(i1_1[r], mk);
                float n2 = fminf(fminf(m2_1[r], o2), fmaxf(m1_1[r], o1));
                bool sel = (o1 < m1_1[r]) || (o1 == m1_1[r] && oi < i1_1[r]);
                m1_1[r] = sel ? o1 : m1_1[r];
                i1_1[r] = sel ? oi : i1_1[r];
                m2_1[r] = n2;
            }
        }
    }

    if (l15 == 0) {
#pragma unroll
        for (int r = 0; r < 4; ++r) {
            {
                int rib = wv * 32 + g * 4 + r;
                size_t grow = (size_t)blockRow0 + rib;
                if (m2_0[r] - m1_0[r] >= MARGIN) {
                    idx_lds[rib] = i1_0[r];
                    out[IOFF + grow] = (float)i1_0[r];
                    atomicAdd(&counts[i1_0[r]], 1.0f);
                } else {
                    idx_lds[rib] = -1;
                    int pos = atomicAdd(rccnt, 1);
                    rclist[pos] = (int)grow;
                }
            }
            {
                int rib = wv * 32 + 16 + g * 4 + r;
                size_t grow = (size_t)blockRow0 + rib;
                if (m2_1[r] - m1_1[r] >= MARGIN) {
                    idx_lds[rib] = i1_1[r];
                    out[IOFF + grow] = (float)i1_1[r];
                    atomicAdd(&counts[i1_1[r]], 1.0f);
                } else {
                    idx_lds[rib] = -1;
                    int pos = atomicAdd(rccnt, 1);
                    rclist[pos] = (int)grow;
                }
            }
        }
    }
    __syncthreads();

    // Epilogue for decided rows: quantized + dw atomics (flagged rows skipped;
    // recheck kernel finishes them).
    const size_t blk_f4 = (size_t)blockIdx.x * 2048;   // 128 rows * 16 f4
    const float4* xin4 = reinterpret_cast<const float4*>(x_in);
    const float4* w4g  = reinterpret_cast<const float4*>(weight);
    float4* q4 = reinterpret_cast<float4*>(out + QOFF);
#pragma unroll
    for (int j = 0; j < 8; ++j) {
        int f4i = tid + j * 256;
        int rl  = f4i >> 4;
        int d4  = f4i & 15;
        int idx = idx_lds[rl];
        if (idx < 0) continue;
        float4 xq = xin4[blk_f4 + f4i];
        float4 wq = w4g[idx * 16 + d4];
        float4 qv;
        qv.x = __fadd_rn(xq.x, __fsub_rn(wq.x, xq.x));
        qv.y = __fadd_rn(xq.y, __fsub_rn(wq.y, xq.y));
        qv.z = __fadd_rn(xq.z, __fsub_rn(wq.z, xq.z));
        qv.w = __fadd_rn(xq.w, __fsub_rn(wq.w, xq.w));
        q4[blk_f4 + f4i] = qv;
        float* dwp = dw + (size_t)idx * DD + d4 * 4;
        atomicAdd(dwp + 0, xq.x);
        atomicAdd(dwp + 1, xq.y);
        atomicAdd(dwp + 2, xq.z);
        atomicAdd(dwp + 3, xq.w);
    }
}

// ---- Kernel C: exact recheck for flagged rows ----
// 256 blocks x 256 thr. Grid-stride over flagged list in chunks of 32 rows.
// Weight staged tile-by-tile in LDS (64 codes x 66 padded). Each lane owns
// one row (lane&31) and half the code range (lane>>5); exact R5 arithmetic.
__global__ void vq_recheck(
    const float* __restrict__ x_in, const float* __restrict__ weight,
    const float* __restrict__ code_sq, float* __restrict__ out,
    float* __restrict__ counts, float* __restrict__ dw,
    const int* __restrict__ rccnt, const int* __restrict__ rclist) {

    __shared__ float lds_w[64 * 66];
    __shared__ float lds_csq[64];
    __shared__ float sbv[4][32];
    __shared__ int   sbi[4][32];
    __shared__ int   idx_lds[32];

    const int tid  = threadIdx.x;
    const int lane = tid & 63;
    const int wv   = tid >> 6;
    const int rl   = lane & 31;
    const int ch   = lane >> 5;

    const int nrc = *rccnt;
    const float4* xin4 = reinterpret_cast<const float4*>(x_in);

    for (int chunk0 = blockIdx.x * 32; chunk0 < nrc; chunk0 += gridDim.x * 32) {
        const int nrows = min(32, nrc - chunk0);
        const bool rowok = rl < nrows;
        const int grow = rowok ? rclist[chunk0 + rl] : rclist[chunk0];

        float4 x4[16];
#pragma unroll
        for (int i = 0; i < 16; ++i) x4[i] = xin4[(size_t)grow * 16 + i];
        const float rs = rowsq4(x4);

        float best = INFINITY;
        int bidx = 0x7fffffff;

        for (int tile = 0; tile < 16; ++tile) {
            __syncthreads();
            // Stage 64-code weight tile into padded LDS.
#pragma unroll
            for (int jj = 0; jj < 4; ++jj) {
                int f4i = tid + jj * 256;         // 1024 f4 per tile
                int cl  = f4i >> 4;
                int d4  = f4i & 15;
                float4 v = *reinterpret_cast<const float4*>(
                    weight + (size_t)(tile * 64 + cl) * DD + d4 * 4);
                float* dst = lds_w + cl * 66 + d4 * 4;
                dst[0] = v.x; dst[1] = v.y; dst[2] = v.z; dst[3] = v.w;
            }
            if (tid < 64) lds_csq[tid] = code_sq[tile * 64 + tid];
            __syncthreads();

#pragma unroll
            for (int j = 0; j < 8; ++j) {
                int cl = (wv * 2 + ch) * 8 + j;
                const float* wr = lds_w + cl * 66;
                float a0 = 0.f, a1 = 0.f, a2 = 0.f, a3 = 0.f;
#pragma unroll
                for (int i = 0; i < 16; ++i) {
                    a0 += x4[i].x * wr[4 * i + 0];
                    a1 += x4[i].y * wr[4 * i + 1];
                    a2 += x4[i].z * wr[4 * i + 2];
                    a3 += x4[i].w * wr[4 * i + 3];
                }
                float dot = (a0 + a1) + (a2 + a3);
                float csq = lds_csq[cl];
                float s = __fsub_rn(__fadd_rn(rs, csq), __fmul_rn(2.0f, dot));
                int code = tile * 64 + cl;
                if (s < best || (s == best && code < bidx)) { best = s; bidx = code; }
            }
        }

        // Combine the two code-halves (lane pair l, l+32).
        {
            float ov = __shfl_xor(best, 32);
            int   oi = __shfl_xor(bidx, 32);
            if (ov < best || (ov == best && oi < bidx)) { best = ov; bidx = oi; }
        }
        if (ch == 0 && rl < 32) { sbv[wv][rl] = best; sbi[wv][rl] = bidx; }
        __syncthreads();
        if (wv == 0 && lane < 32) {
            float bv = sbv[0][lane]; int bi = sbi[0][lane];
#pragma unroll
            for (int s = 1; s < 4; ++s) {
                float v = sbv[s][lane]; int i = sbi[s][lane];
                if (v < bv || (v == bv && i < bi)) { bv = v; bi = i; }
            }
            idx_lds[lane] = bi;
            if (lane < nrows) {
                int gr = rclist[chunk0 + lane];
                out[IOFF + gr] = (float)bi;
                atomicAdd(&counts[bi], 1.0f);
            }
        }
        __syncthreads();

        // Epilogue: 32 rows x 16 f4 = 512 f4 over 256 thr = 2 iters.
        const float4* w4g = reinterpret_cast<const float4*>(weight);
        float4* q4 = reinterpret_cast<float4*>(out + QOFF);
#pragma unroll
        for (int jj = 0; jj < 2; ++jj) {
            int f4i = tid + jj * 256;
            int rr  = f4i >> 4;
            int d4  = f4i & 15;
            if (rr >= nrows) continue;
            int gr  = rclist[chunk0 + rr];
            int idx = idx_lds[rr];
            float4 xq = xin4[(size_t)gr * 16 + d4];
            float4 wq = w4g[idx * 16 + d4];
            float4 qv;
            qv.x = __fadd_rn(xq.x, __fsub_rn(wq.x, xq.x));
            qv.y = __fadd_rn(xq.y, __fsub_rn(wq.y, xq.y));
            qv.z = __fadd_rn(xq.z, __fsub_rn(wq.z, xq.z));
            qv.w = __fadd_rn(xq.w, __fsub_rn(wq.w, xq.w));
            q4[(size_t)gr * 16 + d4] = qv;
            float* dwp = dw + (size_t)idx * DD + d4 * 4;
            atomicAdd(dwp + 0, xq.x);
            atomicAdd(dwp + 1, xq.y);
            atomicAdd(dwp + 2, xq.z);
            atomicAdd(dwp + 3, xq.w);
        }
        __syncthreads();
    }
}

// ---- Kernel D: cs update + normalize ----
__global__ void finalize_cs(const float* __restrict__ cluster_size,
                            const float* __restrict__ counts,
                            float* __restrict__ out,
                            float* __restrict__ cs_fin) {
    __shared__ float sb[1024];
    int k = threadIdx.x;
    float c = 0.99f * cluster_size[k] + 0.01f * counts[k];
    sb[k] = c;
    __syncthreads();
    for (int off = 512; off > 0; off >>= 1) {
        if (k < off) sb[k] += sb[k + off];
        __syncthreads();
    }
    float n = sb[0];
    float v = ((c + 1e-5f) / (n + 0.01024f)) * n;
    out[CSOFF + k] = v;
    cs_fin[k] = v;
}

// ---- Kernel E: EMA embed_avg + new weights ----
__global__ void finalize_w(const float* __restrict__ embed_avg,
                           const float* __restrict__ dw,
                           const float* __restrict__ cs_fin,
                           float* __restrict__ out) {
    int e = blockIdx.x * blockDim.x + threadIdx.x;
    if (e >= KC * DD) return;
    float na = 0.99f * embed_avg[e] + 0.01f * dw[e];
    float nw = na / cs_fin[e >> 6];
    out[EAOFF + e] = na;
    out[WOFF + e] = nw;
}

extern "C" void kernel_launch(void* const* d_in, const int* in_sizes, int n_in,
                              void* d_out, int out_size, void* d_ws, size_t ws_size,
                              hipStream_t stream) {
    (void)in_sizes; (void)n_in; (void)out_size; (void)ws_size;
    const float* x       = (const float*)d_in[0];
    const float* weight  = (const float*)d_in[1];
    const float* cluster = (const float*)d_in[2];
    const float* eavg    = (const float*)d_in[3];
    float* out = (float*)d_out;
    float* wsf = (float*)d_ws;

    float*     code_sq = wsf + WS_CODESQ;
    float*     counts  = wsf + WS_COUNTS;
    float*     dwbuf   = wsf + WS_DW;
    int*       rccnt   = (int*)(wsf + WS_RCCNT);
    float*     cs_fin  = wsf + WS_CSFIN;
    _Float16*  wf16    = (_Float16*)(wsf + WS_WF16);
    int*       rclist  = (int*)(wsf + WS_RCLIST);

    // zero counts + dw + rccnt (contiguous region: floats 1024..67600)
    (void)hipMemsetAsync(counts, 0, (size_t)(67600 - 1024) * sizeof(float), stream);

    hipLaunchKernelGGL(prep_kernel, dim3(4), dim3(256), 0, stream,
                       weight, code_sq, wf16);
    hipLaunchKernelGGL(vq_scan, dim3(512), dim3(256), 0, stream,
                       x, weight, code_sq, wf16, out, counts, dwbuf, rccnt, rclist);
    hipLaunchKernelGGL(vq_recheck, dim3(256), dim3(256), 0, stream,
                       x, weight, code_sq, out, counts, dwbuf, rccnt, rclist);
    hipLaunchKernelGGL(finalize_cs, dim3(1), dim3(1024), 0, stream,
                       cluster, counts, out, cs_fin);
    hipLaunchKernelGGL(finalize_w, dim3(256), dim3(256), 0, stream,
                       eavg, dwbuf, cs_fin, out);
}

// Round 7
// 296.780 us; speedup vs baseline: 1.7095x; 1.7095x over previous
//
#include <hip/hip_runtime.h>

// Problem constants
#define NROWS 65536   // 64*64*32*32 / 64
#define KC    1024
#define DD    64

// Output layout (floats) in d_out
#define QOFF  0                     // quantized_st: 4194304
#define IOFF  4194304               // indices:        65536
#define WOFF  4259840               // new_weight:     65536
#define CSOFF 4325376               // cs:              1024
#define EAOFF 4326400               // new_embed_avg:  65536

// Workspace layout (float offsets)
#define WS_CODESQ  0        // 1024 f
#define WS_COUNTS  1024     // 1024 f
#define WS_RCCNT   2048     // 16 int
#define WS_CURSOR  2064     // 1024 int
#define WS_OFFS    3088     // 1024 int
#define WS_CSFIN   4112     // 1024 f
#define WS_DW      5136     // 65536 f
#define WS_WHI     70672    // 65536 halves (32768 f)
#define WS_WLO     103440   // 65536 halves (32768 f)
#define WS_IDX     136208   // 65536 int
#define WS_RCLIST  201744   // 65536 int
#define WS_ROWLIST 267280   // 65536 int

#define MARGIN 5e-5f

typedef _Float16 half8 __attribute__((ext_vector_type(8)));
typedef float    floatx4 __attribute__((ext_vector_type(4)));

// POD 4-float vector usable through address_space(4) pointers.
struct F4 { float x, y, z, w; };
typedef const __attribute__((address_space(4))) F4    c4F4;
typedef const __attribute__((address_space(4))) float c4f;

// Exact rowsq: numpy pairwise order over float4-held row (R5/R6 proven).
__device__ __forceinline__ float rowsq4(const float4* xv) {
    float4 re, ro;
    re.x = __fmul_rn(xv[0].x, xv[0].x); re.y = __fmul_rn(xv[0].y, xv[0].y);
    re.z = __fmul_rn(xv[0].z, xv[0].z); re.w = __fmul_rn(xv[0].w, xv[0].w);
    ro.x = __fmul_rn(xv[1].x, xv[1].x); ro.y = __fmul_rn(xv[1].y, xv[1].y);
    ro.z = __fmul_rn(xv[1].z, xv[1].z); ro.w = __fmul_rn(xv[1].w, xv[1].w);
#pragma unroll
    for (int i = 2; i < 16; i += 2) {
        re.x = __fadd_rn(re.x, __fmul_rn(xv[i].x, xv[i].x));
        re.y = __fadd_rn(re.y, __fmul_rn(xv[i].y, xv[i].y));
        re.z = __fadd_rn(re.z, __fmul_rn(xv[i].z, xv[i].z));
        re.w = __fadd_rn(re.w, __fmul_rn(xv[i].w, xv[i].w));
        ro.x = __fadd_rn(ro.x, __fmul_rn(xv[i + 1].x, xv[i + 1].x));
        ro.y = __fadd_rn(ro.y, __fmul_rn(xv[i + 1].y, xv[i + 1].y));
        ro.z = __fadd_rn(ro.z, __fmul_rn(xv[i + 1].z, xv[i + 1].z));
        ro.w = __fadd_rn(ro.w, __fmul_rn(xv[i + 1].w, xv[i + 1].w));
    }
    return __fadd_rn(__fadd_rn(__fadd_rn(re.x, re.y), __fadd_rn(re.z, re.w)),
                     __fadd_rn(__fadd_rn(ro.x, ro.y), __fadd_rn(ro.z, ro.w)));
}

// ---- Kernel A: exact code_sq + split-f16 codebook (1024*w = hi + lo) ----
__global__ void prep_kernel(const float* __restrict__ weight,
                            float* __restrict__ code_sq,
                            _Float16* __restrict__ whi,
                            _Float16* __restrict__ wlo) {
    int c = blockIdx.x * blockDim.x + threadIdx.x;
    if (c >= KC) return;
    float4 wv4[16];
    const float4* pw = reinterpret_cast<const float4*>(weight + (size_t)c * DD);
#pragma unroll
    for (int i = 0; i < 16; ++i) wv4[i] = pw[i];
    code_sq[c] = rowsq4(wv4);
    float w64[64];
#pragma unroll
    for (int i = 0; i < 16; ++i) {
        w64[4 * i] = wv4[i].x; w64[4 * i + 1] = wv4[i].y;
        w64[4 * i + 2] = wv4[i].z; w64[4 * i + 3] = wv4[i].w;
    }
#pragma unroll
    for (int j8 = 0; j8 < 8; ++j8) {
        half8 h, l;
#pragma unroll
        for (int j = 0; j < 8; ++j) {
            float s = w64[j8 * 8 + j] * 1024.0f;   // exact (2^10)
            _Float16 hh = (_Float16)s;
            h[j] = hh;
            l[j] = (_Float16)(s - (float)hh);      // exact residual, then rounded
        }
        *reinterpret_cast<half8*>(whi + (size_t)c * DD + j8 * 8) = h;
        *reinterpret_cast<half8*>(wlo + (size_t)c * DD + j8 * 8) = l;
    }
}

// ---- Kernel B: compensated-f16 MFMA scan -> idx or flag. No epilogue. ----
// 512 blocks x 256 thr (4 waves). Block = 128 rows; wave = 32 rows.
// C frag: col(code) = lane&15, row(x-row) = (lane>>4)*4 + reg.
__global__ __launch_bounds__(256) void vq_scan(
    const float* __restrict__ x_in, const float* __restrict__ code_sq,
    const _Float16* __restrict__ whi, const _Float16* __restrict__ wlo,
    float* __restrict__ out, float* __restrict__ counts,
    int* __restrict__ idxbuf, int* __restrict__ rccnt, int* __restrict__ rclist) {

    const int tid  = threadIdx.x;
    const int lane = tid & 63;
    const int wv   = tid >> 6;
    const int l15  = lane & 15;
    const int g    = lane >> 4;

    const int blockRow0 = blockIdx.x * 128;
    const int waveRow0  = blockRow0 + wv * 32;

    // A fragments: x rows split into hi/lo f16. [tile(2)][khalf(2)]
    half8 ah[4], al[4];
#pragma unroll
    for (int t = 0; t < 2; ++t) {
#pragma unroll
        for (int kh = 0; kh < 2; ++kh) {
            const float* p = x_in + (size_t)(waveRow0 + t * 16 + l15) * DD + kh * 32 + g * 8;
            half8 hh, ll;
#pragma unroll
            for (int j = 0; j < 8; ++j) {
                float v = p[j];
                _Float16 h = (_Float16)v;
                hh[j] = h;
                ll[j] = (_Float16)(v - (float)h);
            }
            ah[t * 2 + kh] = hh;
            al[t * 2 + kh] = ll;
        }
    }

    float m1[2][4], m2[2][4];
    int   i1[2][4];
#pragma unroll
    for (int t = 0; t < 2; ++t)
#pragma unroll
        for (int r = 0; r < 4; ++r) { m1[t][r] = INFINITY; m2[t][r] = INFINITY; i1[t][r] = 0; }

    for (int ct = 0; ct < 64; ++ct) {
        const int code = ct * 16 + l15;
        const half8 bh0 = *reinterpret_cast<const half8*>(whi + (size_t)code * DD + g * 8);
        const half8 bh1 = *reinterpret_cast<const half8*>(whi + (size_t)code * DD + 32 + g * 8);
        const half8 bl0 = *reinterpret_cast<const half8*>(wlo + (size_t)code * DD + g * 8);
        const half8 bl1 = *reinterpret_cast<const half8*>(wlo + (size_t)code * DD + 32 + g * 8);
        const float csq = code_sq[code];

#pragma unroll
        for (int t = 0; t < 2; ++t) {
            floatx4 c = {0.f, 0.f, 0.f, 0.f};
            c = __builtin_amdgcn_mfma_f32_16x16x32_f16(al[t * 2 + 0], bh0, c, 0, 0, 0);
            c = __builtin_amdgcn_mfma_f32_16x16x32_f16(al[t * 2 + 1], bh1, c, 0, 0, 0);
            c = __builtin_amdgcn_mfma_f32_16x16x32_f16(ah[t * 2 + 0], bl0, c, 0, 0, 0);
            c = __builtin_amdgcn_mfma_f32_16x16x32_f16(ah[t * 2 + 1], bl1, c, 0, 0, 0);
            c = __builtin_amdgcn_mfma_f32_16x16x32_f16(ah[t * 2 + 0], bh0, c, 0, 0, 0);
            c = __builtin_amdgcn_mfma_f32_16x16x32_f16(ah[t * 2 + 1], bh1, c, 0, 0, 0);
#pragma unroll
            for (int r = 0; r < 4; ++r) {
                float s = fmaf(c[r], -0x1p-9f, csq);   // csq - 2*dot (c is 1024*dot)
                bool lt = s < m1[t][r];
                m2[t][r] = lt ? m1[t][r] : fminf(m2[t][r], s);
                i1[t][r] = lt ? code : i1[t][r];
                m1[t][r] = lt ? s : m1[t][r];
            }
        }
    }

    // Cross-lane argmin reduce within each 16-lane group (butterfly).
#pragma unroll
    for (int t = 0; t < 2; ++t)
#pragma unroll
        for (int r = 0; r < 4; ++r)
#pragma unroll
            for (int mk = 1; mk < 16; mk <<= 1) {
                float o1 = __shfl_xor(m1[t][r], mk);
                float o2 = __shfl_xor(m2[t][r], mk);
                int   oi = __shfl_xor(i1[t][r], mk);
                float n2 = fminf(fminf(m2[t][r], o2), fmaxf(m1[t][r], o1));
                bool sel = (o1 < m1[t][r]) || (o1 == m1[t][r] && oi < i1[t][r]);
                m1[t][r] = sel ? o1 : m1[t][r];
                i1[t][r] = sel ? oi : i1[t][r];
                m2[t][r] = n2;
            }

    if (l15 == 0) {
#pragma unroll
        for (int t = 0; t < 2; ++t)
#pragma unroll
            for (int r = 0; r < 4; ++r) {
                int rib = wv * 32 + t * 16 + g * 4 + r;
                int grow = blockRow0 + rib;
                if (m2[t][r] - m1[t][r] >= MARGIN) {
                    idxbuf[grow] = i1[t][r];
                    out[IOFF + grow] = (float)i1[t][r];
                    atomicAdd(&counts[i1[t][r]], 1.0f);
                } else {
                    int pos = atomicAdd(rccnt, 1);
                    rclist[pos] = grow;
                }
            }
    }
}

// ---- Kernel C: exact recheck (R5-proven s_load structure) over flagged ----
// 1024 blocks x 256 thr; block = 64 flagged rows; early-exit past list end.
__global__ __launch_bounds__(256, 4) void vq_recheck(
    const float* __restrict__ x_in, const float* __restrict__ weight,
    const float* __restrict__ code_sq, float* __restrict__ out,
    float* __restrict__ counts, int* __restrict__ idxbuf,
    const int* __restrict__ rccnt, const int* __restrict__ rclist) {

    __shared__ float s_best[4 * 64];
    __shared__ int   s_bidx[4 * 64];

    const int nrc = rccnt[0];
    const int rb  = blockIdx.x * 64;
    if (rb >= nrc) return;

    const int tid  = threadIdx.x;
    const int lane = tid & 63;
    const int wvu  = __builtin_amdgcn_readfirstlane(tid >> 6);

    const bool valid = (rb + lane) < nrc;
    const int  grow  = rclist[valid ? rb + lane : rb];

    float4 xv[16];
    const float4* px = reinterpret_cast<const float4*>(x_in + (size_t)grow * DD);
#pragma unroll
    for (int i = 0; i < 16; ++i) xv[i] = px[i];
    const float rs = rowsq4(xv);

    unsigned long long wa = (unsigned long long)(weight + (size_t)wvu * 256 * DD);
    unsigned long long ca = (unsigned long long)(code_sq + wvu * 256);
    unsigned wal = __builtin_amdgcn_readfirstlane((unsigned)wa);
    unsigned wah = __builtin_amdgcn_readfirstlane((unsigned)(wa >> 32));
    unsigned cal = __builtin_amdgcn_readfirstlane((unsigned)ca);
    unsigned cah = __builtin_amdgcn_readfirstlane((unsigned)(ca >> 32));
    c4F4* wb4 = (c4F4*)(((unsigned long long)wah << 32) | wal);
    c4f*  cb  = (c4f*)(((unsigned long long)cah << 32) | cal);

    float best = INFINITY;
    int bidx = 0;

#pragma unroll 2
    for (int k = 0; k < 256; ++k) {
        float a0 = 0.f, a1 = 0.f, a2 = 0.f, a3 = 0.f;
#pragma unroll
        for (int i = 0; i < 16; ++i) {
            F4 w4;
            w4.x = wb4[k * 16 + i].x;
            w4.y = wb4[k * 16 + i].y;
            w4.z = wb4[k * 16 + i].z;
            w4.w = wb4[k * 16 + i].w;
            a0 += xv[i].x * w4.x;
            a1 += xv[i].y * w4.y;
            a2 += xv[i].z * w4.z;
            a3 += xv[i].w * w4.w;
        }
        float dot = (a0 + a1) + (a2 + a3);
        float csq = cb[k];
        float dst = __fsub_rn(__fadd_rn(rs, csq), __fmul_rn(2.0f, dot));
        int kg = wvu * 256 + k;
        if (dst < best) { best = dst; bidx = kg; }
    }

    s_best[wvu * 64 + lane] = best;
    s_bidx[wvu * 64 + lane] = bidx;
    __syncthreads();

    if (wvu == 0) {
        float bvv = s_best[lane];
        int   bii = s_bidx[lane];
#pragma unroll
        for (int s = 1; s < 4; ++s) {
            float v = s_best[s * 64 + lane];
            int   i = s_bidx[s * 64 + lane];
            if (v < bvv || (v == bvv && i < bii)) { bvv = v; bii = i; }
        }
        if (valid) {
            out[IOFF + grow] = (float)bii;
            idxbuf[grow] = bii;
            atomicAdd(&counts[bii], 1.0f);
        }
    }
}

// ---- Kernel D: exclusive-scan counts -> offs; zero cursor ----
__global__ void offsets_kernel(const float* __restrict__ counts,
                               int* __restrict__ offs, int* __restrict__ cursor) {
    __shared__ int sc[1024];
    int k = threadIdx.x;
    int c = (int)counts[k];
    sc[k] = c;
    __syncthreads();
    for (int off = 1; off < 1024; off <<= 1) {
        int v = (k >= off) ? sc[k - off] : 0;
        __syncthreads();
        sc[k] += v;
        __syncthreads();
    }
    offs[k] = sc[k] - c;
    cursor[k] = 0;
}

// ---- Kernel E: scatter rows into per-code buckets ----
__global__ void scatter_kernel(const int* __restrict__ idxbuf,
                               const int* __restrict__ offs,
                               int* __restrict__ cursor,
                               int* __restrict__ rowlist) {
    int r = blockIdx.x * blockDim.x + threadIdx.x;
    if (r >= NROWS) return;
    int k = idxbuf[r];
    int pos = atomicAdd(&cursor[k], 1);
    rowlist[offs[k] + pos] = r;
}

// ---- Kernel F: per-code dw reduction + quantized writes (no atomics) ----
// 1024 blocks (one per code) x 256 thr (4 waves); lane <-> d.
__global__ void dw_q_kernel(const float* __restrict__ x_in,
                            const float* __restrict__ weight,
                            const float* __restrict__ counts,
                            const int* __restrict__ offs,
                            const int* __restrict__ rowlist,
                            float* __restrict__ out, float* __restrict__ dw) {
    __shared__ float wsh[64];
    __shared__ float part[4][64];

    const int k    = blockIdx.x;
    const int tid  = threadIdx.x;
    const int lane = tid & 63;
    const int wv   = tid >> 6;

    if (tid < 64) wsh[tid] = weight[(size_t)k * DD + tid];
    __syncthreads();

    const int cnt  = (int)counts[k];
    const int base = offs[k];
    const float wk = wsh[lane];

    float acc = 0.f;
    for (int i = wv; i < cnt; i += 4) {
        int r = rowlist[base + i];
        float xq = x_in[(size_t)r * DD + lane];
        out[QOFF + (size_t)r * DD + lane] = __fadd_rn(xq, __fsub_rn(wk, xq));
        acc = __fadd_rn(acc, xq);
    }
    part[wv][lane] = acc;
    __syncthreads();
    if (tid < 64) {
        float s = __fadd_rn(__fadd_rn(part[0][tid], part[1][tid]),
                            __fadd_rn(part[2][tid], part[3][tid]));
        dw[(size_t)k * DD + tid] = s;
    }
}

// ---- Kernel G: cs update + normalize ----
__global__ void finalize_cs(const float* __restrict__ cluster_size,
                            const float* __restrict__ counts,
                            float* __restrict__ out,
                            float* __restrict__ cs_fin) {
    __shared__ float sb[1024];
    int k = threadIdx.x;
    float c = 0.99f * cluster_size[k] + 0.01f * counts[k];
    sb[k] = c;
    __syncthreads();
    for (int off = 512; off > 0; off >>= 1) {
        if (k < off) sb[k] += sb[k + off];
        __syncthreads();
    }
    float n = sb[0];
    float v = ((c + 1e-5f) / (n + 0.01024f)) * n;
    out[CSOFF + k] = v;
    cs_fin[k] = v;
}

// ---- Kernel H: EMA embed_avg + new weights ----
__global__ void finalize_w(const float* __restrict__ embed_avg,
                           const float* __restrict__ dw,
                           const float* __restrict__ cs_fin,
                           float* __restrict__ out) {
    int e = blockIdx.x * blockDim.x + threadIdx.x;
    if (e >= KC * DD) return;
    float na = 0.99f * embed_avg[e] + 0.01f * dw[e];
    float nw = na / cs_fin[e >> 6];
    out[EAOFF + e] = na;
    out[WOFF + e] = nw;
}

extern "C" void kernel_launch(void* const* d_in, const int* in_sizes, int n_in,
                              void* d_out, int out_size, void* d_ws, size_t ws_size,
                              hipStream_t stream) {
    (void)in_sizes; (void)n_in; (void)out_size; (void)ws_size;
    const float* x       = (const float*)d_in[0];
    const float* weight  = (const float*)d_in[1];
    const float* cluster = (const float*)d_in[2];
    const float* eavg    = (const float*)d_in[3];
    float* out = (float*)d_out;
    float* wsf = (float*)d_ws;

    float*    code_sq = wsf + WS_CODESQ;
    float*    counts  = wsf + WS_COUNTS;
    int*      rccnt   = (int*)(wsf + WS_RCCNT);
    int*      cursor  = (int*)(wsf + WS_CURSOR);
    int*      offs    = (int*)(wsf + WS_OFFS);
    float*    cs_fin  = wsf + WS_CSFIN;
    float*    dwbuf   = wsf + WS_DW;
    _Float16* whi     = (_Float16*)(wsf + WS_WHI);
    _Float16* wlo     = (_Float16*)(wsf + WS_WLO);
    int*      idxbuf  = (int*)(wsf + WS_IDX);
    int*      rclist  = (int*)(wsf + WS_RCLIST);
    int*      rowlist = (int*)(wsf + WS_ROWLIST);

    // zero counts + rccnt (contiguous)
    (void)hipMemsetAsync(counts, 0, (size_t)(1024 + 16) * sizeof(float), stream);

    hipLaunchKernelGGL(prep_kernel, dim3(4), dim3(256), 0, stream,
                       weight, code_sq, whi, wlo);
    hipLaunchKernelGGL(vq_scan, dim3(512), dim3(256), 0, stream,
                       x, code_sq, whi, wlo, out, counts, idxbuf, rccnt, rclist);
    hipLaunchKernelGGL(vq_recheck, dim3(1024), dim3(256), 0, stream,
                       x, weight, code_sq, out, counts, idxbuf, rccnt, rclist);
    hipLaunchKernelGGL(offsets_kernel, dim3(1), dim3(1024), 0, stream,
                       counts, offs, cursor);
    hipLaunchKernelGGL(scatter_kernel, dim3(256), dim3(256), 0, stream,
                       idxbuf, offs, cursor, rowlist);
    hipLaunchKernelGGL(dw_q_kernel, dim3(1024), dim3(256), 0, stream,
                       x, weight, counts, offs, rowlist, out, dwbuf);
    hipLaunchKernelGGL(finalize_cs, dim3(1), dim3(1024), 0, stream,
                       cluster, counts, out, cs_fin);
    hipLaunchKernelGGL(finalize_w, dim3(256), dim3(256), 0, stream,
                       eavg, dwbuf, cs_fin, out);
}

// Round 8
// 200.676 us; speedup vs baseline: 2.5282x; 1.4789x over previous
//
#include <hip/hip_runtime.h>

// Problem constants
#define NROWS 65536   // 64*64*32*32 / 64
#define KC    1024
#define KCPAD 1040    // +16 codes padding for scan prefetch
#define DD    64

// Output layout (floats) in d_out
#define QOFF  0                     // quantized_st: 4194304
#define IOFF  4194304               // indices:        65536
#define WOFF  4259840               // new_weight:     65536
#define CSOFF 4325376               // cs:              1024
#define EAOFF 4326400               // new_embed_avg:  65536

// Workspace layout (float offsets)
#define WS_CODESQ  0        // 1056 f (1040 used)
#define WS_COUNTS  1056     // 1024 f
#define WS_RCCNT   2080     // 16 int
#define WS_CURSOR  2096     // 1024 int
#define WS_OFFS    3120     // 1024 int
#define WS_CSFIN   4144     // 1024 f
#define WS_DW      5168     // 65536 f
#define WS_WHI     70704    // 66560 halves = 33280 f (1040 codes x 64)
#define WS_WLO     103984   // 33280 f
#define WS_IDX     137264   // 65536 int
#define WS_RCLIST  202800   // 65536 int
#define WS_ROWLIST 268336   // 65536 int
#define WS_PACKED  333872   // 65536 u64 = 131072 f (8B-aligned)

#define MARGIN 5e-5f

typedef _Float16 half8 __attribute__((ext_vector_type(8)));
typedef float    floatx4 __attribute__((ext_vector_type(4)));

// POD 4-float vector usable through address_space(4) pointers.
struct F4 { float x, y, z, w; };
typedef const __attribute__((address_space(4))) F4    c4F4;
typedef const __attribute__((address_space(4))) float c4f;

__device__ __forceinline__ unsigned f2ord(float f) {
    unsigned u = __float_as_uint(f);
    return (u & 0x80000000u) ? ~u : (u | 0x80000000u);
}

// Exact rowsq: numpy pairwise order over float4-held row (R5-R7 proven).
__device__ __forceinline__ float rowsq4(const float4* xv) {
    float4 re, ro;
    re.x = __fmul_rn(xv[0].x, xv[0].x); re.y = __fmul_rn(xv[0].y, xv[0].y);
    re.z = __fmul_rn(xv[0].z, xv[0].z); re.w = __fmul_rn(xv[0].w, xv[0].w);
    ro.x = __fmul_rn(xv[1].x, xv[1].x); ro.y = __fmul_rn(xv[1].y, xv[1].y);
    ro.z = __fmul_rn(xv[1].z, xv[1].z); ro.w = __fmul_rn(xv[1].w, xv[1].w);
#pragma unroll
    for (int i = 2; i < 16; i += 2) {
        re.x = __fadd_rn(re.x, __fmul_rn(xv[i].x, xv[i].x));
        re.y = __fadd_rn(re.y, __fmul_rn(xv[i].y, xv[i].y));
        re.z = __fadd_rn(re.z, __fmul_rn(xv[i].z, xv[i].z));
        re.w = __fadd_rn(re.w, __fmul_rn(xv[i].w, xv[i].w));
        ro.x = __fadd_rn(ro.x, __fmul_rn(xv[i + 1].x, xv[i + 1].x));
        ro.y = __fadd_rn(ro.y, __fmul_rn(xv[i + 1].y, xv[i + 1].y));
        ro.z = __fadd_rn(ro.z, __fmul_rn(xv[i + 1].z, xv[i + 1].z));
        ro.w = __fadd_rn(ro.w, __fmul_rn(xv[i + 1].w, xv[i + 1].w));
    }
    return __fadd_rn(__fadd_rn(__fadd_rn(re.x, re.y), __fadd_rn(re.z, re.w)),
                     __fadd_rn(__fadd_rn(ro.x, ro.y), __fadd_rn(ro.z, ro.w)));
}

// ---- Kernel A: exact code_sq + split-f16 codebook (1024*w = hi + lo) ----
__global__ void prep_kernel(const float* __restrict__ weight,
                            float* __restrict__ code_sq,
                            _Float16* __restrict__ whi,
                            _Float16* __restrict__ wlo) {
    int c = blockIdx.x * blockDim.x + threadIdx.x;
    if (c >= KC) return;
    float4 wv4[16];
    const float4* pw = reinterpret_cast<const float4*>(weight + (size_t)c * DD);
#pragma unroll
    for (int i = 0; i < 16; ++i) wv4[i] = pw[i];
    code_sq[c] = rowsq4(wv4);
    float w64[64];
#pragma unroll
    for (int i = 0; i < 16; ++i) {
        w64[4 * i] = wv4[i].x; w64[4 * i + 1] = wv4[i].y;
        w64[4 * i + 2] = wv4[i].z; w64[4 * i + 3] = wv4[i].w;
    }
#pragma unroll
    for (int j8 = 0; j8 < 8; ++j8) {
        half8 h, l;
#pragma unroll
        for (int j = 0; j < 8; ++j) {
            float s = w64[j8 * 8 + j] * 1024.0f;   // exact (2^10)
            _Float16 hh = (_Float16)s;
            h[j] = hh;
            l[j] = (_Float16)(s - (float)hh);      // exact residual, rounded
        }
        *reinterpret_cast<half8*>(whi + (size_t)c * DD + j8 * 8) = h;
        *reinterpret_cast<half8*>(wlo + (size_t)c * DD + j8 * 8) = l;
    }
}

// ---- Kernel B: compensated-f16 MFMA scan with B-prefetch ----
// 512 blocks x 256 thr (4 waves). Block = 128 rows; wave = 32 rows.
__global__ __launch_bounds__(256) void vq_scan(
    const float* __restrict__ x_in, const float* __restrict__ code_sq,
    const _Float16* __restrict__ whi, const _Float16* __restrict__ wlo,
    float* __restrict__ out, float* __restrict__ counts,
    int* __restrict__ idxbuf, int* __restrict__ rccnt, int* __restrict__ rclist) {

    const int tid  = threadIdx.x;
    const int lane = tid & 63;
    const int wv   = tid >> 6;
    const int l15  = lane & 15;
    const int g    = lane >> 4;

    const int blockRow0 = blockIdx.x * 128;
    const int waveRow0  = blockRow0 + wv * 32;

    // A fragments: x rows split into hi/lo f16. [tile(2)][khalf(2)]
    half8 ah[4], al[4];
#pragma unroll
    for (int t = 0; t < 2; ++t) {
#pragma unroll
        for (int kh = 0; kh < 2; ++kh) {
            const float* p = x_in + (size_t)(waveRow0 + t * 16 + l15) * DD + kh * 32 + g * 8;
            half8 hh, ll;
#pragma unroll
            for (int j = 0; j < 8; ++j) {
                float v = p[j];
                _Float16 h = (_Float16)v;
                hh[j] = h;
                ll[j] = (_Float16)(v - (float)h);
            }
            ah[t * 2 + kh] = hh;
            al[t * 2 + kh] = ll;
        }
    }

    float m1[2][4], m2[2][4];
    int   i1[2][4];
#pragma unroll
    for (int t = 0; t < 2; ++t)
#pragma unroll
        for (int r = 0; r < 4; ++r) { m1[t][r] = INFINITY; m2[t][r] = INFINITY; i1[t][r] = 0; }

    // Prefetch rotation: load ct's B-frags before the loop; in iter ct load ct+1.
    int code = l15;
    half8 bh0 = *reinterpret_cast<const half8*>(whi + (size_t)code * DD + g * 8);
    half8 bh1 = *reinterpret_cast<const half8*>(whi + (size_t)code * DD + 32 + g * 8);
    half8 bl0 = *reinterpret_cast<const half8*>(wlo + (size_t)code * DD + g * 8);
    half8 bl1 = *reinterpret_cast<const half8*>(wlo + (size_t)code * DD + 32 + g * 8);
    float csq = code_sq[code];

    for (int ct = 0; ct < 64; ++ct) {
        const int ncode = code + 16;   // padded codebook: safe at ct=63
        half8 nbh0 = *reinterpret_cast<const half8*>(whi + (size_t)ncode * DD + g * 8);
        half8 nbh1 = *reinterpret_cast<const half8*>(whi + (size_t)ncode * DD + 32 + g * 8);
        half8 nbl0 = *reinterpret_cast<const half8*>(wlo + (size_t)ncode * DD + g * 8);
        half8 nbl1 = *reinterpret_cast<const half8*>(wlo + (size_t)ncode * DD + 32 + g * 8);
        float ncsq = code_sq[ncode];

#pragma unroll
        for (int t = 0; t < 2; ++t) {
            floatx4 c = {0.f, 0.f, 0.f, 0.f};
            c = __builtin_amdgcn_mfma_f32_16x16x32_f16(al[t * 2 + 0], bh0, c, 0, 0, 0);
            c = __builtin_amdgcn_mfma_f32_16x16x32_f16(al[t * 2 + 1], bh1, c, 0, 0, 0);
            c = __builtin_amdgcn_mfma_f32_16x16x32_f16(ah[t * 2 + 0], bl0, c, 0, 0, 0);
            c = __builtin_amdgcn_mfma_f32_16x16x32_f16(ah[t * 2 + 1], bl1, c, 0, 0, 0);
            c = __builtin_amdgcn_mfma_f32_16x16x32_f16(ah[t * 2 + 0], bh0, c, 0, 0, 0);
            c = __builtin_amdgcn_mfma_f32_16x16x32_f16(ah[t * 2 + 1], bh1, c, 0, 0, 0);
#pragma unroll
            for (int r = 0; r < 4; ++r) {
                float s = fmaf(c[r], -0x1p-9f, csq);   // csq - 2*dot
                bool lt = s < m1[t][r];
                m2[t][r] = lt ? m1[t][r] : fminf(m2[t][r], s);
                i1[t][r] = lt ? code : i1[t][r];
                m1[t][r] = lt ? s : m1[t][r];
            }
        }
        bh0 = nbh0; bh1 = nbh1; bl0 = nbl0; bl1 = nbl1; csq = ncsq; code = ncode;
    }

    // Cross-lane argmin reduce within each 16-lane group (butterfly).
#pragma unroll
    for (int t = 0; t < 2; ++t)
#pragma unroll
        for (int r = 0; r < 4; ++r)
#pragma unroll
            for (int mk = 1; mk < 16; mk <<= 1) {
                float o1 = __shfl_xor(m1[t][r], mk);
                float o2 = __shfl_xor(m2[t][r], mk);
                int   oi = __shfl_xor(i1[t][r], mk);
                float n2 = fminf(fminf(m2[t][r], o2), fmaxf(m1[t][r], o1));
                bool sel = (o1 < m1[t][r]) || (o1 == m1[t][r] && oi < i1[t][r]);
                m1[t][r] = sel ? o1 : m1[t][r];
                i1[t][r] = sel ? oi : i1[t][r];
                m2[t][r] = n2;
            }

    if (l15 == 0) {
#pragma unroll
        for (int t = 0; t < 2; ++t)
#pragma unroll
            for (int r = 0; r < 4; ++r) {
                int rib = wv * 32 + t * 16 + g * 4 + r;
                int grow = blockRow0 + rib;
                if (m2[t][r] - m1[t][r] >= MARGIN) {
                    idxbuf[grow] = i1[t][r];
                    out[IOFF + grow] = (float)i1[t][r];
                    atomicAdd(&counts[i1[t][r]], 1.0f);
                } else {
                    int pos = atomicAdd(rccnt, 1);
                    rclist[pos] = grow;
                }
            }
    }
}

// ---- Kernel C: exact recheck, parallel over (64-row chunk) x (64-code chunk) ----
// Fixed 2048 blocks, grid-stride over items. Wave handles 16 codes via s_load;
// each lane owns one row; partial winner combined by packed u64 atomicMin.
__global__ __launch_bounds__(256, 4) void vq_recheck(
    const float* __restrict__ x_in, const float* __restrict__ weight,
    const float* __restrict__ code_sq,
    unsigned long long* __restrict__ packed,
    const int* __restrict__ rccnt, const int* __restrict__ rclist) {

    const int nrc = rccnt[0];
    const int nitems = ((nrc + 63) >> 6) * 16;

    const int tid  = threadIdx.x;
    const int lane = tid & 63;
    const int wvu  = __builtin_amdgcn_readfirstlane(tid >> 6);

    for (int item = blockIdx.x; item < nitems; item += gridDim.x) {
        const int rb     = (item >> 4) * 64;
        const int cchunk = item & 15;
        const bool valid = (rb + lane) < nrc;
        const int  grow  = rclist[valid ? rb + lane : rb];

        float4 xv[16];
        const float4* px = reinterpret_cast<const float4*>(x_in + (size_t)grow * DD);
#pragma unroll
        for (int i = 0; i < 16; ++i) xv[i] = px[i];
        const float rs = rowsq4(xv);

        const int k0 = cchunk * 64 + wvu * 16;    // wave-uniform
        unsigned long long wa = (unsigned long long)(weight + (size_t)k0 * DD);
        unsigned long long ca = (unsigned long long)(code_sq + k0);
        unsigned wal = __builtin_amdgcn_readfirstlane((unsigned)wa);
        unsigned wah = __builtin_amdgcn_readfirstlane((unsigned)(wa >> 32));
        unsigned cal = __builtin_amdgcn_readfirstlane((unsigned)ca);
        unsigned cah = __builtin_amdgcn_readfirstlane((unsigned)(ca >> 32));
        c4F4* wb4 = (c4F4*)(((unsigned long long)wah << 32) | wal);
        c4f*  cb  = (c4f*)(((unsigned long long)cah << 32) | cal);

        float best = INFINITY;
        int bidx = 0x7fffffff;

#pragma unroll 2
        for (int k = 0; k < 16; ++k) {
            float a0 = 0.f, a1 = 0.f, a2 = 0.f, a3 = 0.f;
#pragma unroll
            for (int i = 0; i < 16; ++i) {
                F4 w4;
                w4.x = wb4[k * 16 + i].x;
                w4.y = wb4[k * 16 + i].y;
                w4.z = wb4[k * 16 + i].z;
                w4.w = wb4[k * 16 + i].w;
                a0 += xv[i].x * w4.x;
                a1 += xv[i].y * w4.y;
                a2 += xv[i].z * w4.z;
                a3 += xv[i].w * w4.w;
            }
            float dot = (a0 + a1) + (a2 + a3);
            float csq = cb[k];
            float dst = __fsub_rn(__fadd_rn(rs, csq), __fmul_rn(2.0f, dot));
            int kg = k0 + k;
            if (dst < best) { best = dst; bidx = kg; }   // ascending k: lowest idx on tie
        }

        if (valid) {
            unsigned long long p =
                ((unsigned long long)f2ord(best) << 32) | (unsigned)bidx;
            atomicMin(&packed[grow], p);
        }
    }
}

// ---- Kernel C2: unpack winners for flagged rows ----
__global__ void rc_finalize(const unsigned long long* __restrict__ packed,
                            const int* __restrict__ rccnt,
                            const int* __restrict__ rclist,
                            float* __restrict__ out, float* __restrict__ counts,
                            int* __restrict__ idxbuf) {
    int i = blockIdx.x * blockDim.x + threadIdx.x;
    if (i >= rccnt[0]) return;
    int grow = rclist[i];
    int bidx = (int)(packed[grow] & 0xFFFFFFFFull);
    out[IOFF + grow] = (float)bidx;
    idxbuf[grow] = bidx;
    atomicAdd(&counts[bidx], 1.0f);
}

// ---- Kernel D: exclusive-scan counts -> offs; zero cursor ----
__global__ void offsets_kernel(const float* __restrict__ counts,
                               int* __restrict__ offs, int* __restrict__ cursor) {
    __shared__ int sc[1024];
    int k = threadIdx.x;
    int c = (int)counts[k];
    sc[k] = c;
    __syncthreads();
    for (int off = 1; off < 1024; off <<= 1) {
        int v = (k >= off) ? sc[k - off] : 0;
        __syncthreads();
        sc[k] += v;
        __syncthreads();
    }
    offs[k] = sc[k] - c;
    cursor[k] = 0;
}

// ---- Kernel E: scatter rows into per-code buckets ----
__global__ void scatter_kernel(const int* __restrict__ idxbuf,
                               const int* __restrict__ offs,
                               int* __restrict__ cursor,
                               int* __restrict__ rowlist) {
    int r = blockIdx.x * blockDim.x + threadIdx.x;
    if (r >= NROWS) return;
    int k = idxbuf[r];
    int pos = atomicAdd(&cursor[k], 1);
    rowlist[offs[k] + pos] = r;
}

// ---- Kernel F: per-code dw reduction + quantized writes (no atomics) ----
__global__ void dw_q_kernel(const float* __restrict__ x_in,
                            const float* __restrict__ weight,
                            const float* __restrict__ counts,
                            const int* __restrict__ offs,
                            const int* __restrict__ rowlist,
                            float* __restrict__ out, float* __restrict__ dw) {
    __shared__ float wsh[64];
    __shared__ float part[4][64];

    const int k    = blockIdx.x;
    const int tid  = threadIdx.x;
    const int lane = tid & 63;
    const int wv   = tid >> 6;

    if (tid < 64) wsh[tid] = weight[(size_t)k * DD + tid];
    __syncthreads();

    const int cnt  = (int)counts[k];
    const int base = offs[k];
    const float wk = wsh[lane];

    float acc = 0.f;
    for (int i = wv; i < cnt; i += 4) {
        int r = rowlist[base + i];
        float xq = x_in[(size_t)r * DD + lane];
        out[QOFF + (size_t)r * DD + lane] = __fadd_rn(xq, __fsub_rn(wk, xq));
        acc = __fadd_rn(acc, xq);
    }
    part[wv][lane] = acc;
    __syncthreads();
    if (tid < 64) {
        float s = __fadd_rn(__fadd_rn(part[0][tid], part[1][tid]),
                            __fadd_rn(part[2][tid], part[3][tid]));
        dw[(size_t)k * DD + tid] = s;
    }
}

// ---- Kernel G: cs update + normalize ----
__global__ void finalize_cs(const float* __restrict__ cluster_size,
                            const float* __restrict__ counts,
                            float* __restrict__ out,
                            float* __restrict__ cs_fin) {
    __shared__ float sb[1024];
    int k = threadIdx.x;
    float c = 0.99f * cluster_size[k] + 0.01f * counts[k];
    sb[k] = c;
    __syncthreads();
    for (int off = 512; off > 0; off >>= 1) {
        if (k < off) sb[k] += sb[k + off];
        __syncthreads();
    }
    float n = sb[0];
    float v = ((c + 1e-5f) / (n + 0.01024f)) * n;
    out[CSOFF + k] = v;
    cs_fin[k] = v;
}

// ---- Kernel H: EMA embed_avg + new weights ----
__global__ void finalize_w(const float* __restrict__ embed_avg,
                           const float* __restrict__ dw,
                           const float* __restrict__ cs_fin,
                           float* __restrict__ out) {
    int e = blockIdx.x * blockDim.x + threadIdx.x;
    if (e >= KC * DD) return;
    float na = 0.99f * embed_avg[e] + 0.01f * dw[e];
    float nw = na / cs_fin[e >> 6];
    out[EAOFF + e] = na;
    out[WOFF + e] = nw;
}

extern "C" void kernel_launch(void* const* d_in, const int* in_sizes, int n_in,
                              void* d_out, int out_size, void* d_ws, size_t ws_size,
                              hipStream_t stream) {
    (void)in_sizes; (void)n_in; (void)out_size; (void)ws_size;
    const float* x       = (const float*)d_in[0];
    const float* weight  = (const float*)d_in[1];
    const float* cluster = (const float*)d_in[2];
    const float* eavg    = (const float*)d_in[3];
    float* out = (float*)d_out;
    float* wsf = (float*)d_ws;

    float*    code_sq = wsf + WS_CODESQ;
    float*    counts  = wsf + WS_COUNTS;
    int*      rccnt   = (int*)(wsf + WS_RCCNT);
    int*      cursor  = (int*)(wsf + WS_CURSOR);
    int*      offs    = (int*)(wsf + WS_OFFS);
    float*    cs_fin  = wsf + WS_CSFIN;
    float*    dwbuf   = wsf + WS_DW;
    _Float16* whi     = (_Float16*)(wsf + WS_WHI);
    _Float16* wlo     = (_Float16*)(wsf + WS_WLO);
    int*      idxbuf  = (int*)(wsf + WS_IDX);
    int*      rclist  = (int*)(wsf + WS_RCLIST);
    int*      rowlist = (int*)(wsf + WS_ROWLIST);
    unsigned long long* packed = (unsigned long long*)(wsf + WS_PACKED);

    // zero counts + rccnt (contiguous); init packed to all-ones (max u64)
    (void)hipMemsetAsync(counts, 0, (size_t)(1024 + 16) * sizeof(float), stream);
    (void)hipMemsetAsync(packed, 0xFF, (size_t)NROWS * 8, stream);

    hipLaunchKernelGGL(prep_kernel, dim3(16), dim3(64), 0, stream,
                       weight, code_sq, whi, wlo);
    hipLaunchKernelGGL(vq_scan, dim3(512), dim3(256), 0, stream,
                       x, code_sq, whi, wlo, out, counts, idxbuf, rccnt, rclist);
    hipLaunchKernelGGL(vq_recheck, dim3(2048), dim3(256), 0, stream,
                       x, weight, code_sq, packed, rccnt, rclist);
    hipLaunchKernelGGL(rc_finalize, dim3(256), dim3(256), 0, stream,
                       packed, rccnt, rclist, out, counts, idxbuf);
    hipLaunchKernelGGL(offsets_kernel, dim3(1), dim3(1024), 0, stream,
                       counts, offs, cursor);
    hipLaunchKernelGGL(scatter_kernel, dim3(256), dim3(256), 0, stream,
                       idxbuf, offs, cursor, rowlist);
    hipLaunchKernelGGL(dw_q_kernel, dim3(1024), dim3(256), 0, stream,
                       x, weight, counts, offs, rowlist, out, dwbuf);
    hipLaunchKernelGGL(finalize_cs, dim3(1), dim3(1024), 0, stream,
                       cluster, counts, out, cs_fin);
    hipLaunchKernelGGL(finalize_w, dim3(256), dim3(256), 0, stream,
                       eavg, dwbuf, cs_fin, out);
}

// Round 9
// 163.086 us; speedup vs baseline: 3.1109x; 1.2305x over previous
//
#include <hip/hip_runtime.h>

// Problem constants
#define NROWS 65536   // 64*64*32*32 / 64
#define KC    1024
#define KCPAD 1040    // +16 codes padding for scan prefetch
#define DD    64

// Output layout (floats) in d_out
#define QOFF  0                     // quantized_st: 4194304
#define IOFF  4194304               // indices:        65536
#define WOFF  4259840               // new_weight:     65536
#define CSOFF 4325376               // cs:              1024
#define EAOFF 4326400               // new_embed_avg:  65536

// Workspace layout (float offsets)
#define WS_CODESQ  0        // 1056 f (1040 used)
#define WS_COUNTS  1056     // 1024 f
#define WS_RCCNT   2080     // 16 int
#define WS_CURSOR  2096     // 1024 int
#define WS_OFFS    3120     // 1024 int
#define WS_CSFIN   4144     // 1024 f
#define WS_DW      5168     // 65536 f
#define WS_WHI     70704    // 66560 halves = 33280 f (1040 codes x 64)
#define WS_WLO     103984   // 33280 f
#define WS_IDX     137264   // 65536 int
#define WS_RCLIST  202800   // 65536 int
#define WS_ROWLIST 268336   // 65536 int
#define WS_PACKED  333872   // 65536 u64 = 131072 f (8B-aligned)

#define MARGIN 5e-5f

typedef _Float16 half8 __attribute__((ext_vector_type(8)));
typedef float    floatx4 __attribute__((ext_vector_type(4)));

// POD 4-float vector usable through address_space(4) pointers.
struct F4 { float x, y, z, w; };
typedef const __attribute__((address_space(4))) F4    c4F4;
typedef const __attribute__((address_space(4))) float c4f;

__device__ __forceinline__ unsigned f2ord(float f) {
    unsigned u = __float_as_uint(f);
    return (u & 0x80000000u) ? ~u : (u | 0x80000000u);
}

// Exact rowsq: numpy pairwise order over float4-held row (R5-R8 proven).
__device__ __forceinline__ float rowsq4(const float4* xv) {
    float4 re, ro;
    re.x = __fmul_rn(xv[0].x, xv[0].x); re.y = __fmul_rn(xv[0].y, xv[0].y);
    re.z = __fmul_rn(xv[0].z, xv[0].z); re.w = __fmul_rn(xv[0].w, xv[0].w);
    ro.x = __fmul_rn(xv[1].x, xv[1].x); ro.y = __fmul_rn(xv[1].y, xv[1].y);
    ro.z = __fmul_rn(xv[1].z, xv[1].z); ro.w = __fmul_rn(xv[1].w, xv[1].w);
#pragma unroll
    for (int i = 2; i < 16; i += 2) {
        re.x = __fadd_rn(re.x, __fmul_rn(xv[i].x, xv[i].x));
        re.y = __fadd_rn(re.y, __fmul_rn(xv[i].y, xv[i].y));
        re.z = __fadd_rn(re.z, __fmul_rn(xv[i].z, xv[i].z));
        re.w = __fadd_rn(re.w, __fmul_rn(xv[i].w, xv[i].w));
        ro.x = __fadd_rn(ro.x, __fmul_rn(xv[i + 1].x, xv[i + 1].x));
        ro.y = __fadd_rn(ro.y, __fmul_rn(xv[i + 1].y, xv[i + 1].y));
        ro.z = __fadd_rn(ro.z, __fmul_rn(xv[i + 1].z, xv[i + 1].z));
        ro.w = __fadd_rn(ro.w, __fmul_rn(xv[i + 1].w, xv[i + 1].w));
    }
    return __fadd_rn(__fadd_rn(__fadd_rn(re.x, re.y), __fadd_rn(re.z, re.w)),
                     __fadd_rn(__fadd_rn(ro.x, ro.y), __fadd_rn(ro.z, ro.w)));
}

// ---- Kernel A: exact code_sq + split-f16 codebook (1024*w = hi + lo) ----
__global__ void prep_kernel(const float* __restrict__ weight,
                            float* __restrict__ code_sq,
                            _Float16* __restrict__ whi,
                            _Float16* __restrict__ wlo) {
    int c = blockIdx.x * blockDim.x + threadIdx.x;
    if (c >= KC) return;
    float4 wv4[16];
    const float4* pw = reinterpret_cast<const float4*>(weight + (size_t)c * DD);
#pragma unroll
    for (int i = 0; i < 16; ++i) wv4[i] = pw[i];
    code_sq[c] = rowsq4(wv4);
    float w64[64];
#pragma unroll
    for (int i = 0; i < 16; ++i) {
        w64[4 * i] = wv4[i].x; w64[4 * i + 1] = wv4[i].y;
        w64[4 * i + 2] = wv4[i].z; w64[4 * i + 3] = wv4[i].w;
    }
#pragma unroll
    for (int j8 = 0; j8 < 8; ++j8) {
        half8 h, l;
#pragma unroll
        for (int j = 0; j < 8; ++j) {
            float s = w64[j8 * 8 + j] * 1024.0f;   // exact (2^10)
            _Float16 hh = (_Float16)s;
            h[j] = hh;
            l[j] = (_Float16)(s - (float)hh);      // exact residual, rounded
        }
        *reinterpret_cast<half8*>(whi + (size_t)c * DD + j8 * 8) = h;
        *reinterpret_cast<half8*>(wlo + (size_t)c * DD + j8 * 8) = l;
    }
}

// ---- Kernel B: compensated-f16 MFMA scan, K-split x4 for occupancy ----
// 2048 blocks x 256 thr (4 waves). Block = 32 rows; every wave holds the same
// 32 rows in A-frags and scans a 256-code quarter (16 iters, depth-1 prefetch).
// Partial (m1,m2,i1) merged across waves in LDS, exact lexicographic.
__global__ __launch_bounds__(256) void vq_scan(
    const float* __restrict__ x_in, const float* __restrict__ code_sq,
    const _Float16* __restrict__ whi, const _Float16* __restrict__ wlo,
    float* __restrict__ out, float* __restrict__ counts,
    int* __restrict__ idxbuf, int* __restrict__ rccnt, int* __restrict__ rclist) {

    __shared__ float sm1[4][32], sm2[4][32];
    __shared__ int   si1[4][32];

    const int tid  = threadIdx.x;
    const int lane = tid & 63;
    const int wv   = tid >> 6;
    const int l15  = lane & 15;
    const int g    = lane >> 4;

    const int blockRow0 = blockIdx.x * 32;

    // A fragments: 32 rows split into hi/lo f16. [tile(2)][khalf(2)]
    half8 ah[4], al[4];
#pragma unroll
    for (int t = 0; t < 2; ++t) {
#pragma unroll
        for (int kh = 0; kh < 2; ++kh) {
            const float* p = x_in + (size_t)(blockRow0 + t * 16 + l15) * DD + kh * 32 + g * 8;
            half8 hh, ll;
#pragma unroll
            for (int j = 0; j < 8; ++j) {
                float v = p[j];
                _Float16 h = (_Float16)v;
                hh[j] = h;
                ll[j] = (_Float16)(v - (float)h);
            }
            ah[t * 2 + kh] = hh;
            al[t * 2 + kh] = ll;
        }
    }

    float m1[2][4], m2[2][4];
    int   i1[2][4];
#pragma unroll
    for (int t = 0; t < 2; ++t)
#pragma unroll
        for (int r = 0; r < 4; ++r) { m1[t][r] = INFINITY; m2[t][r] = INFINITY; i1[t][r] = 0; }

    // Wave's code quarter with depth-1 prefetch (padded codebook: last
    // prefetch reads codes [kbase+256, +16) which exist up to 1040).
    int code = wv * 256 + l15;
    half8 bh0 = *reinterpret_cast<const half8*>(whi + (size_t)code * DD + g * 8);
    half8 bh1 = *reinterpret_cast<const half8*>(whi + (size_t)code * DD + 32 + g * 8);
    half8 bl0 = *reinterpret_cast<const half8*>(wlo + (size_t)code * DD + g * 8);
    half8 bl1 = *reinterpret_cast<const half8*>(wlo + (size_t)code * DD + 32 + g * 8);
    float csq = code_sq[code];

    for (int ct = 0; ct < 16; ++ct) {
        const int ncode = code + 16;
        half8 nbh0 = *reinterpret_cast<const half8*>(whi + (size_t)ncode * DD + g * 8);
        half8 nbh1 = *reinterpret_cast<const half8*>(whi + (size_t)ncode * DD + 32 + g * 8);
        half8 nbl0 = *reinterpret_cast<const half8*>(wlo + (size_t)ncode * DD + g * 8);
        half8 nbl1 = *reinterpret_cast<const half8*>(wlo + (size_t)ncode * DD + 32 + g * 8);
        float ncsq = code_sq[ncode];

#pragma unroll
        for (int t = 0; t < 2; ++t) {
            floatx4 c = {0.f, 0.f, 0.f, 0.f};
            c = __builtin_amdgcn_mfma_f32_16x16x32_f16(al[t * 2 + 0], bh0, c, 0, 0, 0);
            c = __builtin_amdgcn_mfma_f32_16x16x32_f16(al[t * 2 + 1], bh1, c, 0, 0, 0);
            c = __builtin_amdgcn_mfma_f32_16x16x32_f16(ah[t * 2 + 0], bl0, c, 0, 0, 0);
            c = __builtin_amdgcn_mfma_f32_16x16x32_f16(ah[t * 2 + 1], bl1, c, 0, 0, 0);
            c = __builtin_amdgcn_mfma_f32_16x16x32_f16(ah[t * 2 + 0], bh0, c, 0, 0, 0);
            c = __builtin_amdgcn_mfma_f32_16x16x32_f16(ah[t * 2 + 1], bh1, c, 0, 0, 0);
#pragma unroll
            for (int r = 0; r < 4; ++r) {
                float s = fmaf(c[r], -0x1p-9f, csq);   // csq - 2*dot
                bool lt = s < m1[t][r];
                m2[t][r] = lt ? m1[t][r] : fminf(m2[t][r], s);
                i1[t][r] = lt ? code : i1[t][r];
                m1[t][r] = lt ? s : m1[t][r];
            }
        }
        bh0 = nbh0; bh1 = nbh1; bl0 = nbl0; bl1 = nbl1; csq = ncsq; code = ncode;
    }

    // Cross-lane argmin reduce within each 16-lane group (butterfly).
#pragma unroll
    for (int t = 0; t < 2; ++t)
#pragma unroll
        for (int r = 0; r < 4; ++r)
#pragma unroll
            for (int mk = 1; mk < 16; mk <<= 1) {
                float o1 = __shfl_xor(m1[t][r], mk);
                float o2 = __shfl_xor(m2[t][r], mk);
                int   oi = __shfl_xor(i1[t][r], mk);
                float n2 = fminf(fminf(m2[t][r], o2), fmaxf(m1[t][r], o1));
                bool sel = (o1 < m1[t][r]) || (o1 == m1[t][r] && oi < i1[t][r]);
                m1[t][r] = sel ? o1 : m1[t][r];
                i1[t][r] = sel ? oi : i1[t][r];
                m2[t][r] = n2;
            }

    // Publish per-wave partials (8 rows per l15==0 lane).
    if (l15 == 0) {
#pragma unroll
        for (int t = 0; t < 2; ++t)
#pragma unroll
            for (int r = 0; r < 4; ++r) {
                int rib = t * 16 + g * 4 + r;
                sm1[wv][rib] = m1[t][r];
                sm2[wv][rib] = m2[t][r];
                si1[wv][rib] = i1[t][r];
            }
    }
    __syncthreads();

    // Merge 4 wave-partials per row; threads 0..31 own one row each.
    if (tid < 32) {
        float bm1 = INFINITY, bm2 = INFINITY;
        int bi = 0x7fffffff;
#pragma unroll
        for (int s = 0; s < 4; ++s) {
            float v1 = sm1[s][tid];
            float v2 = sm2[s][tid];
            int   vi = si1[s][tid];
            if (v1 < bm1 || (v1 == bm1 && vi < bi)) {
                bm2 = fminf(bm1, v2);
                bm1 = v1; bi = vi;
            } else {
                bm2 = fminf(bm2, v1);
            }
        }
        int grow = blockRow0 + tid;
        if (bm2 - bm1 >= MARGIN) {
            idxbuf[grow] = bi;
            out[IOFF + grow] = (float)bi;
            atomicAdd(&counts[bi], 1.0f);
        } else {
            int pos = atomicAdd(rccnt, 1);
            rclist[pos] = grow;
        }
    }
}

// ---- Kernel C: exact recheck, parallel over (64-row chunk) x (64-code chunk) ----
__global__ __launch_bounds__(256, 4) void vq_recheck(
    const float* __restrict__ x_in, const float* __restrict__ weight,
    const float* __restrict__ code_sq,
    unsigned long long* __restrict__ packed,
    const int* __restrict__ rccnt, const int* __restrict__ rclist) {

    const int nrc = rccnt[0];
    const int nitems = ((nrc + 63) >> 6) * 16;

    const int tid  = threadIdx.x;
    const int lane = tid & 63;
    const int wvu  = __builtin_amdgcn_readfirstlane(tid >> 6);

    for (int item = blockIdx.x; item < nitems; item += gridDim.x) {
        const int rb     = (item >> 4) * 64;
        const int cchunk = item & 15;
        const bool valid = (rb + lane) < nrc;
        const int  grow  = rclist[valid ? rb + lane : rb];

        float4 xv[16];
        const float4* px = reinterpret_cast<const float4*>(x_in + (size_t)grow * DD);
#pragma unroll
        for (int i = 0; i < 16; ++i) xv[i] = px[i];
        const float rs = rowsq4(xv);

        const int k0 = cchunk * 64 + wvu * 16;    // wave-uniform
        unsigned long long wa = (unsigned long long)(weight + (size_t)k0 * DD);
        unsigned long long ca = (unsigned long long)(code_sq + k0);
        unsigned wal = __builtin_amdgcn_readfirstlane((unsigned)wa);
        unsigned wah = __builtin_amdgcn_readfirstlane((unsigned)(wa >> 32));
        unsigned cal = __builtin_amdgcn_readfirstlane((unsigned)ca);
        unsigned cah = __builtin_amdgcn_readfirstlane((unsigned)(ca >> 32));
        c4F4* wb4 = (c4F4*)(((unsigned long long)wah << 32) | wal);
        c4f*  cb  = (c4f*)(((unsigned long long)cah << 32) | cal);

        float best = INFINITY;
        int bidx = 0x7fffffff;

#pragma unroll 2
        for (int k = 0; k < 16; ++k) {
            float a0 = 0.f, a1 = 0.f, a2 = 0.f, a3 = 0.f;
#pragma unroll
            for (int i = 0; i < 16; ++i) {
                F4 w4;
                w4.x = wb4[k * 16 + i].x;
                w4.y = wb4[k * 16 + i].y;
                w4.z = wb4[k * 16 + i].z;
                w4.w = wb4[k * 16 + i].w;
                a0 += xv[i].x * w4.x;
                a1 += xv[i].y * w4.y;
                a2 += xv[i].z * w4.z;
                a3 += xv[i].w * w4.w;
            }
            float dot = (a0 + a1) + (a2 + a3);
            float csq = cb[k];
            float dst = __fsub_rn(__fadd_rn(rs, csq), __fmul_rn(2.0f, dot));
            int kg = k0 + k;
            if (dst < best) { best = dst; bidx = kg; }
        }

        if (valid) {
            unsigned long long p =
                ((unsigned long long)f2ord(best) << 32) | (unsigned)bidx;
            atomicMin(&packed[grow], p);
        }
    }
}

// ---- Kernel C2: unpack winners for flagged rows ----
__global__ void rc_finalize(const unsigned long long* __restrict__ packed,
                            const int* __restrict__ rccnt,
                            const int* __restrict__ rclist,
                            float* __restrict__ out, float* __restrict__ counts,
                            int* __restrict__ idxbuf) {
    int i = blockIdx.x * blockDim.x + threadIdx.x;
    if (i >= rccnt[0]) return;
    int grow = rclist[i];
    int bidx = (int)(packed[grow] & 0xFFFFFFFFull);
    out[IOFF + grow] = (float)bidx;
    idxbuf[grow] = bidx;
    atomicAdd(&counts[bidx], 1.0f);
}

// ---- Kernel D: fused exclusive-scan (offs) + cs normalize; 1 block ----
__global__ void offsets_cs_kernel(const float* __restrict__ counts,
                                  const float* __restrict__ cluster_size,
                                  int* __restrict__ offs, int* __restrict__ cursor,
                                  float* __restrict__ out, float* __restrict__ cs_fin) {
    __shared__ int   sc[1024];
    __shared__ float sb[1024];
    int k = threadIdx.x;
    int c = (int)counts[k];
    float ce = 0.99f * cluster_size[k] + 0.01f * counts[k];
    sc[k] = c;
    sb[k] = ce;
    __syncthreads();
    for (int off = 1; off < 1024; off <<= 1) {
        int v = (k >= off) ? sc[k - off] : 0;
        __syncthreads();
        sc[k] += v;
        __syncthreads();
    }
    offs[k] = sc[k] - c;
    cursor[k] = 0;
    for (int off = 512; off > 0; off >>= 1) {
        if (k < off) sb[k] += sb[k + off];
        __syncthreads();
    }
    float n = sb[0];
    float v = ((ce + 1e-5f) / (n + 0.01024f)) * n;
    out[CSOFF + k] = v;
    cs_fin[k] = v;
}

// ---- Kernel E: scatter rows into per-code buckets ----
__global__ void scatter_kernel(const int* __restrict__ idxbuf,
                               const int* __restrict__ offs,
                               int* __restrict__ cursor,
                               int* __restrict__ rowlist) {
    int r = blockIdx.x * blockDim.x + threadIdx.x;
    if (r >= NROWS) return;
    int k = idxbuf[r];
    int pos = atomicAdd(&cursor[k], 1);
    rowlist[offs[k] + pos] = r;
}

// ---- Kernel F: per-code dw reduction + quantized writes (4-deep ILP) ----
__global__ void dw_q_kernel(const float* __restrict__ x_in,
                            const float* __restrict__ weight,
                            const float* __restrict__ counts,
                            const int* __restrict__ offs,
                            const int* __restrict__ rowlist,
                            float* __restrict__ out, float* __restrict__ dw) {
    __shared__ float wsh[64];
    __shared__ float part[4][64];

    const int k    = blockIdx.x;
    const int tid  = threadIdx.x;
    const int lane = tid & 63;
    const int wv   = tid >> 6;

    if (tid < 64) wsh[tid] = weight[(size_t)k * DD + tid];
    __syncthreads();

    const int cnt  = (int)counts[k];
    const int base = offs[k];
    const float wk = wsh[lane];

    float acc = 0.f;
    int i = wv;
    // 4 rows in flight per wave (same per-wave summation order as stride-4 loop)
    for (; i + 12 < cnt; i += 16) {
        int r0 = rowlist[base + i];
        int r1 = rowlist[base + i + 4];
        int r2 = rowlist[base + i + 8];
        int r3 = rowlist[base + i + 12];
        float x0 = x_in[(size_t)r0 * DD + lane];
        float x1 = x_in[(size_t)r1 * DD + lane];
        float x2 = x_in[(size_t)r2 * DD + lane];
        float x3 = x_in[(size_t)r3 * DD + lane];
        out[QOFF + (size_t)r0 * DD + lane] = __fadd_rn(x0, __fsub_rn(wk, x0));
        out[QOFF + (size_t)r1 * DD + lane] = __fadd_rn(x1, __fsub_rn(wk, x1));
        out[QOFF + (size_t)r2 * DD + lane] = __fadd_rn(x2, __fsub_rn(wk, x2));
        out[QOFF + (size_t)r3 * DD + lane] = __fadd_rn(x3, __fsub_rn(wk, x3));
        acc = __fadd_rn(acc, x0);
        acc = __fadd_rn(acc, x1);
        acc = __fadd_rn(acc, x2);
        acc = __fadd_rn(acc, x3);
    }
    for (; i < cnt; i += 4) {
        int r = rowlist[base + i];
        float xq = x_in[(size_t)r * DD + lane];
        out[QOFF + (size_t)r * DD + lane] = __fadd_rn(xq, __fsub_rn(wk, xq));
        acc = __fadd_rn(acc, xq);
    }
    part[wv][lane] = acc;
    __syncthreads();
    if (tid < 64) {
        float s = __fadd_rn(__fadd_rn(part[0][tid], part[1][tid]),
                            __fadd_rn(part[2][tid], part[3][tid]));
        dw[(size_t)k * DD + tid] = s;
    }
}

// ---- Kernel G: EMA embed_avg + new weights ----
__global__ void finalize_w(const float* __restrict__ embed_avg,
                           const float* __restrict__ dw,
                           const float* __restrict__ cs_fin,
                           float* __restrict__ out) {
    int e = blockIdx.x * blockDim.x + threadIdx.x;
    if (e >= KC * DD) return;
    float na = 0.99f * embed_avg[e] + 0.01f * dw[e];
    float nw = na / cs_fin[e >> 6];
    out[EAOFF + e] = na;
    out[WOFF + e] = nw;
}

extern "C" void kernel_launch(void* const* d_in, const int* in_sizes, int n_in,
                              void* d_out, int out_size, void* d_ws, size_t ws_size,
                              hipStream_t stream) {
    (void)in_sizes; (void)n_in; (void)out_size; (void)ws_size;
    const float* x       = (const float*)d_in[0];
    const float* weight  = (const float*)d_in[1];
    const float* cluster = (const float*)d_in[2];
    const float* eavg    = (const float*)d_in[3];
    float* out = (float*)d_out;
    float* wsf = (float*)d_ws;

    float*    code_sq = wsf + WS_CODESQ;
    float*    counts  = wsf + WS_COUNTS;
    int*      rccnt   = (int*)(wsf + WS_RCCNT);
    int*      cursor  = (int*)(wsf + WS_CURSOR);
    int*      offs    = (int*)(wsf + WS_OFFS);
    float*    cs_fin  = wsf + WS_CSFIN;
    float*    dwbuf   = wsf + WS_DW;
    _Float16* whi     = (_Float16*)(wsf + WS_WHI);
    _Float16* wlo     = (_Float16*)(wsf + WS_WLO);
    int*      idxbuf  = (int*)(wsf + WS_IDX);
    int*      rclist  = (int*)(wsf + WS_RCLIST);
    int*      rowlist = (int*)(wsf + WS_ROWLIST);
    unsigned long long* packed = (unsigned long long*)(wsf + WS_PACKED);

    // zero counts + rccnt (contiguous); init packed to all-ones (max u64)
    (void)hipMemsetAsync(counts, 0, (size_t)(1024 + 16) * sizeof(float), stream);
    (void)hipMemsetAsync(packed, 0xFF, (size_t)NROWS * 8, stream);

    hipLaunchKernelGGL(prep_kernel, dim3(16), dim3(64), 0, stream,
                       weight, code_sq, whi, wlo);
    hipLaunchKernelGGL(vq_scan, dim3(2048), dim3(256), 0, stream,
                       x, code_sq, whi, wlo, out, counts, idxbuf, rccnt, rclist);
    hipLaunchKernelGGL(vq_recheck, dim3(2048), dim3(256), 0, stream,
                       x, weight, code_sq, packed, rccnt, rclist);
    hipLaunchKernelGGL(rc_finalize, dim3(256), dim3(256), 0, stream,
                       packed, rccnt, rclist, out, counts, idxbuf);
    hipLaunchKernelGGL(offsets_cs_kernel, dim3(1), dim3(1024), 0, stream,
                       counts, cluster, offs, cursor, out, cs_fin);
    hipLaunchKernelGGL(scatter_kernel, dim3(256), dim3(256), 0, stream,
                       idxbuf, offs, cursor, rowlist);
    hipLaunchKernelGGL(dw_q_kernel, dim3(1024), dim3(256), 0, stream,
                       x, weight, counts, offs, rowlist, out, dwbuf);
    hipLaunchKernelGGL(finalize_w, dim3(256), dim3(256), 0, stream,
                       eavg, dwbuf, cs_fin, out);
}

// Round 10
// 146.536 us; speedup vs baseline: 3.4622x; 1.1129x over previous
//
#include <hip/hip_runtime.h>

// Problem constants
#define NROWS 65536   // 64*64*32*32 / 64
#define KC    1024
#define KCPAD 1040    // +16 codes padding for scan prefetch
#define DD    64

// Output layout (floats) in d_out
#define QOFF  0                     // quantized_st: 4194304
#define IOFF  4194304               // indices:        65536
#define WOFF  4259840               // new_weight:     65536
#define CSOFF 4325376               // cs:              1024
#define EAOFF 4326400               // new_embed_avg:  65536

// Workspace layout (float offsets)
#define WS_CODESQ  0        // 1056 f (1040 used)
#define WS_COUNTS  1056     // 1024 f
#define WS_RCCNT   2080     // 16 int
#define WS_CURSOR  2096     // 1024 int
#define WS_OFFS    3120     // 1024 int
#define WS_CSFIN   4144     // 1024 f
#define WS_DW      5168     // 65536 f
#define WS_WHI     70704    // 66560 halves = 33280 f (1040 codes x 64)
#define WS_WLO     103984   // 33280 f
#define WS_IDX     137264   // 65536 int
#define WS_RCLIST  202800   // 65536 int
#define WS_ROWLIST 268336   // 65536 int
#define WS_PACKED  333872   // 65536 u64 = 131072 f (8B-aligned)

#define MARGIN 5e-5f

typedef _Float16 half8 __attribute__((ext_vector_type(8)));
typedef float    floatx4 __attribute__((ext_vector_type(4)));

// POD 4-float vector usable through address_space(4) pointers.
struct F4 { float x, y, z, w; };
typedef const __attribute__((address_space(4))) F4    c4F4;
typedef const __attribute__((address_space(4))) float c4f;

__device__ __forceinline__ unsigned f2ord(float f) {
    unsigned u = __float_as_uint(f);
    return (u & 0x80000000u) ? ~u : (u | 0x80000000u);
}

// Exact rowsq: numpy pairwise order over float4-held row (R5-R9 proven).
__device__ __forceinline__ float rowsq4(const float4* xv) {
    float4 re, ro;
    re.x = __fmul_rn(xv[0].x, xv[0].x); re.y = __fmul_rn(xv[0].y, xv[0].y);
    re.z = __fmul_rn(xv[0].z, xv[0].z); re.w = __fmul_rn(xv[0].w, xv[0].w);
    ro.x = __fmul_rn(xv[1].x, xv[1].x); ro.y = __fmul_rn(xv[1].y, xv[1].y);
    ro.z = __fmul_rn(xv[1].z, xv[1].z); ro.w = __fmul_rn(xv[1].w, xv[1].w);
#pragma unroll
    for (int i = 2; i < 16; i += 2) {
        re.x = __fadd_rn(re.x, __fmul_rn(xv[i].x, xv[i].x));
        re.y = __fadd_rn(re.y, __fmul_rn(xv[i].y, xv[i].y));
        re.z = __fadd_rn(re.z, __fmul_rn(xv[i].z, xv[i].z));
        re.w = __fadd_rn(re.w, __fmul_rn(xv[i].w, xv[i].w));
        ro.x = __fadd_rn(ro.x, __fmul_rn(xv[i + 1].x, xv[i + 1].x));
        ro.y = __fadd_rn(ro.y, __fmul_rn(xv[i + 1].y, xv[i + 1].y));
        ro.z = __fadd_rn(ro.z, __fmul_rn(xv[i + 1].z, xv[i + 1].z));
        ro.w = __fadd_rn(ro.w, __fmul_rn(xv[i + 1].w, xv[i + 1].w));
    }
    return __fadd_rn(__fadd_rn(__fadd_rn(re.x, re.y), __fadd_rn(re.z, re.w)),
                     __fadd_rn(__fadd_rn(ro.x, ro.y), __fadd_rn(ro.z, ro.w)));
}

// ---- Kernel A: exact code_sq + split-f16 codebook + zero counts/rccnt ----
__global__ void prep_kernel(const float* __restrict__ weight,
                            float* __restrict__ code_sq,
                            _Float16* __restrict__ whi,
                            _Float16* __restrict__ wlo,
                            float* __restrict__ counts,
                            int* __restrict__ rccnt) {
    int c = blockIdx.x * blockDim.x + threadIdx.x;
    if (c >= KC) return;
    counts[c] = 0.0f;
    if (c == 0) rccnt[0] = 0;
    float4 wv4[16];
    const float4* pw = reinterpret_cast<const float4*>(weight + (size_t)c * DD);
#pragma unroll
    for (int i = 0; i < 16; ++i) wv4[i] = pw[i];
    code_sq[c] = rowsq4(wv4);
    float w64[64];
#pragma unroll
    for (int i = 0; i < 16; ++i) {
        w64[4 * i] = wv4[i].x; w64[4 * i + 1] = wv4[i].y;
        w64[4 * i + 2] = wv4[i].z; w64[4 * i + 3] = wv4[i].w;
    }
#pragma unroll
    for (int j8 = 0; j8 < 8; ++j8) {
        half8 h, l;
#pragma unroll
        for (int j = 0; j < 8; ++j) {
            float s = w64[j8 * 8 + j] * 1024.0f;   // exact (2^10)
            _Float16 hh = (_Float16)s;
            h[j] = hh;
            l[j] = (_Float16)(s - (float)hh);      // exact residual, rounded
        }
        *reinterpret_cast<half8*>(whi + (size_t)c * DD + j8 * 8) = h;
        *reinterpret_cast<half8*>(wlo + (size_t)c * DD + j8 * 8) = l;
    }
}

// ---- Kernel B: compensated-f16 MFMA scan; 4 M-tiles/wave + K-split x4 ----
// 1024 blocks x 256 thr (4 waves). Block = 64 rows; every wave holds the same
// 64 rows (4 M-tiles) in A-frags, scans a 256-code quarter (16 iters, depth-1
// prefetch). 4 B-loads feed 24 MFMAs/iter -> latency hidden by ILP not TLP.
__global__ __launch_bounds__(256, 2) void vq_scan(
    const float* __restrict__ x_in, const float* __restrict__ code_sq,
    const _Float16* __restrict__ whi, const _Float16* __restrict__ wlo,
    float* __restrict__ out, float* __restrict__ counts,
    int* __restrict__ idxbuf, int* __restrict__ rccnt, int* __restrict__ rclist) {

    __shared__ float sm1[4][64], sm2[4][64];
    __shared__ int   si1[4][64];

    const int tid  = threadIdx.x;
    const int lane = tid & 63;
    const int wv   = tid >> 6;
    const int l15  = lane & 15;
    const int g    = lane >> 4;

    const int blockRow0 = blockIdx.x * 64;

    // A fragments: 64 rows split into hi/lo f16. [tile(4)][khalf(2)]
    half8 ah[8], al[8];
#pragma unroll
    for (int t = 0; t < 4; ++t) {
#pragma unroll
        for (int kh = 0; kh < 2; ++kh) {
            const float4* p4 = reinterpret_cast<const float4*>(
                x_in + (size_t)(blockRow0 + t * 16 + l15) * DD + kh * 32 + g * 8);
            float4 v0 = p4[0], v1 = p4[1];
            float vals[8] = {v0.x, v0.y, v0.z, v0.w, v1.x, v1.y, v1.z, v1.w};
            half8 hh, ll;
#pragma unroll
            for (int j = 0; j < 8; ++j) {
                _Float16 h = (_Float16)vals[j];
                hh[j] = h;
                ll[j] = (_Float16)(vals[j] - (float)h);
            }
            ah[t * 2 + kh] = hh;
            al[t * 2 + kh] = ll;
        }
    }

    float m1[4][4], m2[4][4];
    int   i1[4][4];
#pragma unroll
    for (int t = 0; t < 4; ++t)
#pragma unroll
        for (int r = 0; r < 4; ++r) { m1[t][r] = INFINITY; m2[t][r] = INFINITY; i1[t][r] = 0; }

    // Wave's code quarter with depth-1 prefetch (padded codebook).
    int code = wv * 256 + l15;
    half8 bh0 = *reinterpret_cast<const half8*>(whi + (size_t)code * DD + g * 8);
    half8 bh1 = *reinterpret_cast<const half8*>(whi + (size_t)code * DD + 32 + g * 8);
    half8 bl0 = *reinterpret_cast<const half8*>(wlo + (size_t)code * DD + g * 8);
    half8 bl1 = *reinterpret_cast<const half8*>(wlo + (size_t)code * DD + 32 + g * 8);
    float csq = code_sq[code];

    for (int ct = 0; ct < 16; ++ct) {
        const int ncode = code + 16;
        half8 nbh0 = *reinterpret_cast<const half8*>(whi + (size_t)ncode * DD + g * 8);
        half8 nbh1 = *reinterpret_cast<const half8*>(whi + (size_t)ncode * DD + 32 + g * 8);
        half8 nbl0 = *reinterpret_cast<const half8*>(wlo + (size_t)ncode * DD + g * 8);
        half8 nbl1 = *reinterpret_cast<const half8*>(wlo + (size_t)ncode * DD + 32 + g * 8);
        float ncsq = code_sq[ncode];

#pragma unroll
        for (int t = 0; t < 4; ++t) {
            floatx4 c = {0.f, 0.f, 0.f, 0.f};
            c = __builtin_amdgcn_mfma_f32_16x16x32_f16(al[t * 2 + 0], bh0, c, 0, 0, 0);
            c = __builtin_amdgcn_mfma_f32_16x16x32_f16(al[t * 2 + 1], bh1, c, 0, 0, 0);
            c = __builtin_amdgcn_mfma_f32_16x16x32_f16(ah[t * 2 + 0], bl0, c, 0, 0, 0);
            c = __builtin_amdgcn_mfma_f32_16x16x32_f16(ah[t * 2 + 1], bl1, c, 0, 0, 0);
            c = __builtin_amdgcn_mfma_f32_16x16x32_f16(ah[t * 2 + 0], bh0, c, 0, 0, 0);
            c = __builtin_amdgcn_mfma_f32_16x16x32_f16(ah[t * 2 + 1], bh1, c, 0, 0, 0);
#pragma unroll
            for (int r = 0; r < 4; ++r) {
                float s = fmaf(c[r], -0x1p-9f, csq);   // csq - 2*dot
                bool lt = s < m1[t][r];
                m2[t][r] = lt ? m1[t][r] : fminf(m2[t][r], s);
                i1[t][r] = lt ? code : i1[t][r];
                m1[t][r] = lt ? s : m1[t][r];
            }
        }
        bh0 = nbh0; bh1 = nbh1; bl0 = nbl0; bl1 = nbl1; csq = ncsq; code = ncode;
    }

    // Cross-lane argmin reduce within each 16-lane group (butterfly).
#pragma unroll
    for (int t = 0; t < 4; ++t)
#pragma unroll
        for (int r = 0; r < 4; ++r)
#pragma unroll
            for (int mk = 1; mk < 16; mk <<= 1) {
                float o1 = __shfl_xor(m1[t][r], mk);
                float o2 = __shfl_xor(m2[t][r], mk);
                int   oi = __shfl_xor(i1[t][r], mk);
                float n2 = fminf(fminf(m2[t][r], o2), fmaxf(m1[t][r], o1));
                bool sel = (o1 < m1[t][r]) || (o1 == m1[t][r] && oi < i1[t][r]);
                m1[t][r] = sel ? o1 : m1[t][r];
                i1[t][r] = sel ? oi : i1[t][r];
                m2[t][r] = n2;
            }

    // Publish per-wave partials (16 rows per l15==0 lane).
    if (l15 == 0) {
#pragma unroll
        for (int t = 0; t < 4; ++t)
#pragma unroll
            for (int r = 0; r < 4; ++r) {
                int rib = t * 16 + g * 4 + r;
                sm1[wv][rib] = m1[t][r];
                sm2[wv][rib] = m2[t][r];
                si1[wv][rib] = i1[t][r];
            }
    }
    __syncthreads();

    // Merge 4 wave-partials per row; threads 0..63 own one row each.
    if (tid < 64) {
        float bm1 = INFINITY, bm2 = INFINITY;
        int bi = 0x7fffffff;
#pragma unroll
        for (int s = 0; s < 4; ++s) {
            float v1 = sm1[s][tid];
            float v2 = sm2[s][tid];
            int   vi = si1[s][tid];
            if (v1 < bm1 || (v1 == bm1 && vi < bi)) {
                bm2 = fminf(bm1, v2);
                bm1 = v1; bi = vi;
            } else {
                bm2 = fminf(bm2, v1);
            }
        }
        int grow = blockRow0 + tid;
        if (bm2 - bm1 >= MARGIN) {
            idxbuf[grow] = bi;
            out[IOFF + grow] = (float)bi;
            atomicAdd(&counts[bi], 1.0f);
        } else {
            int pos = atomicAdd(rccnt, 1);
            rclist[pos] = grow;
        }
    }
}

// ---- Kernel C: exact recheck, parallel over (64-row chunk) x (64-code chunk) ----
__global__ __launch_bounds__(256, 4) void vq_recheck(
    const float* __restrict__ x_in, const float* __restrict__ weight,
    const float* __restrict__ code_sq,
    unsigned long long* __restrict__ packed,
    const int* __restrict__ rccnt, const int* __restrict__ rclist) {

    const int nrc = rccnt[0];
    const int nitems = ((nrc + 63) >> 6) * 16;

    const int tid  = threadIdx.x;
    const int lane = tid & 63;
    const int wvu  = __builtin_amdgcn_readfirstlane(tid >> 6);

    for (int item = blockIdx.x; item < nitems; item += gridDim.x) {
        const int rb     = (item >> 4) * 64;
        const int cchunk = item & 15;
        const bool valid = (rb + lane) < nrc;
        const int  grow  = rclist[valid ? rb + lane : rb];

        float4 xv[16];
        const float4* px = reinterpret_cast<const float4*>(x_in + (size_t)grow * DD);
#pragma unroll
        for (int i = 0; i < 16; ++i) xv[i] = px[i];
        const float rs = rowsq4(xv);

        const int k0 = cchunk * 64 + wvu * 16;    // wave-uniform
        unsigned long long wa = (unsigned long long)(weight + (size_t)k0 * DD);
        unsigned long long ca = (unsigned long long)(code_sq + k0);
        unsigned wal = __builtin_amdgcn_readfirstlane((unsigned)wa);
        unsigned wah = __builtin_amdgcn_readfirstlane((unsigned)(wa >> 32));
        unsigned cal = __builtin_amdgcn_readfirstlane((unsigned)ca);
        unsigned cah = __builtin_amdgcn_readfirstlane((unsigned)(ca >> 32));
        c4F4* wb4 = (c4F4*)(((unsigned long long)wah << 32) | wal);
        c4f*  cb  = (c4f*)(((unsigned long long)cah << 32) | cal);

        float best = INFINITY;
        int bidx = 0x7fffffff;

#pragma unroll 2
        for (int k = 0; k < 16; ++k) {
            float a0 = 0.f, a1 = 0.f, a2 = 0.f, a3 = 0.f;
#pragma unroll
            for (int i = 0; i < 16; ++i) {
                F4 w4;
                w4.x = wb4[k * 16 + i].x;
                w4.y = wb4[k * 16 + i].y;
                w4.z = wb4[k * 16 + i].z;
                w4.w = wb4[k * 16 + i].w;
                a0 += xv[i].x * w4.x;
                a1 += xv[i].y * w4.y;
                a2 += xv[i].z * w4.z;
                a3 += xv[i].w * w4.w;
            }
            float dot = (a0 + a1) + (a2 + a3);
            float csq = cb[k];
            float dst = __fsub_rn(__fadd_rn(rs, csq), __fmul_rn(2.0f, dot));
            int kg = k0 + k;
            if (dst < best) { best = dst; bidx = kg; }
        }

        if (valid) {
            unsigned long long p =
                ((unsigned long long)f2ord(best) << 32) | (unsigned)bidx;
            atomicMin(&packed[grow], p);
        }
    }
}

// ---- Kernel C2: unpack winners for flagged rows ----
__global__ void rc_finalize(const unsigned long long* __restrict__ packed,
                            const int* __restrict__ rccnt,
                            const int* __restrict__ rclist,
                            float* __restrict__ out, float* __restrict__ counts,
                            int* __restrict__ idxbuf) {
    int i = blockIdx.x * blockDim.x + threadIdx.x;
    if (i >= rccnt[0]) return;
    int grow = rclist[i];
    int bidx = (int)(packed[grow] & 0xFFFFFFFFull);
    out[IOFF + grow] = (float)bidx;
    idxbuf[grow] = bidx;
    atomicAdd(&counts[bidx], 1.0f);
}

// ---- Kernel D: fused exclusive-scan (offs) + cs normalize; 1 block ----
__global__ void offsets_cs_kernel(const float* __restrict__ counts,
                                  const float* __restrict__ cluster_size,
                                  int* __restrict__ offs, int* __restrict__ cursor,
                                  float* __restrict__ out, float* __restrict__ cs_fin) {
    __shared__ int   sc[1024];
    __shared__ float sb[1024];
    int k = threadIdx.x;
    int c = (int)counts[k];
    float ce = 0.99f * cluster_size[k] + 0.01f * counts[k];
    sc[k] = c;
    sb[k] = ce;
    __syncthreads();
    for (int off = 1; off < 1024; off <<= 1) {
        int v = (k >= off) ? sc[k - off] : 0;
        __syncthreads();
        sc[k] += v;
        __syncthreads();
    }
    offs[k] = sc[k] - c;
    cursor[k] = 0;
    for (int off = 512; off > 0; off >>= 1) {
        if (k < off) sb[k] += sb[k + off];
        __syncthreads();
    }
    float n = sb[0];
    float v = ((ce + 1e-5f) / (n + 0.01024f)) * n;
    out[CSOFF + k] = v;
    cs_fin[k] = v;
}

// ---- Kernel E: scatter rows into per-code buckets ----
__global__ void scatter_kernel(const int* __restrict__ idxbuf,
                               const int* __restrict__ offs,
                               int* __restrict__ cursor,
                               int* __restrict__ rowlist) {
    int r = blockIdx.x * blockDim.x + threadIdx.x;
    if (r >= NROWS) return;
    int k = idxbuf[r];
    int pos = atomicAdd(&cursor[k], 1);
    rowlist[offs[k] + pos] = r;
}

// ---- Kernel F: per-code dw reduction + quantized writes (4-deep ILP) ----
__global__ void dw_q_kernel(const float* __restrict__ x_in,
                            const float* __restrict__ weight,
                            const float* __restrict__ counts,
                            const int* __restrict__ offs,
                            const int* __restrict__ rowlist,
                            float* __restrict__ out, float* __restrict__ dw) {
    __shared__ float wsh[64];
    __shared__ float part[4][64];

    const int k    = blockIdx.x;
    const int tid  = threadIdx.x;
    const int lane = tid & 63;
    const int wv   = tid >> 6;

    if (tid < 64) wsh[tid] = weight[(size_t)k * DD + tid];
    __syncthreads();

    const int cnt  = (int)counts[k];
    const int base = offs[k];
    const float wk = wsh[lane];

    float acc = 0.f;
    int i = wv;
    for (; i + 12 < cnt; i += 16) {
        int r0 = rowlist[base + i];
        int r1 = rowlist[base + i + 4];
        int r2 = rowlist[base + i + 8];
        int r3 = rowlist[base + i + 12];
        float x0 = x_in[(size_t)r0 * DD + lane];
        float x1 = x_in[(size_t)r1 * DD + lane];
        float x2 = x_in[(size_t)r2 * DD + lane];
        float x3 = x_in[(size_t)r3 * DD + lane];
        out[QOFF + (size_t)r0 * DD + lane] = __fadd_rn(x0, __fsub_rn(wk, x0));
        out[QOFF + (size_t)r1 * DD + lane] = __fadd_rn(x1, __fsub_rn(wk, x1));
        out[QOFF + (size_t)r2 * DD + lane] = __fadd_rn(x2, __fsub_rn(wk, x2));
        out[QOFF + (size_t)r3 * DD + lane] = __fadd_rn(x3, __fsub_rn(wk, x3));
        acc = __fadd_rn(acc, x0);
        acc = __fadd_rn(acc, x1);
        acc = __fadd_rn(acc, x2);
        acc = __fadd_rn(acc, x3);
    }
    for (; i < cnt; i += 4) {
        int r = rowlist[base + i];
        float xq = x_in[(size_t)r * DD + lane];
        out[QOFF + (size_t)r * DD + lane] = __fadd_rn(xq, __fsub_rn(wk, xq));
        acc = __fadd_rn(acc, xq);
    }
    part[wv][lane] = acc;
    __syncthreads();
    if (tid < 64) {
        float s = __fadd_rn(__fadd_rn(part[0][tid], part[1][tid]),
                            __fadd_rn(part[2][tid], part[3][tid]));
        dw[(size_t)k * DD + tid] = s;
    }
}

// ---- Kernel G: EMA embed_avg + new weights ----
__global__ void finalize_w(const float* __restrict__ embed_avg,
                           const float* __restrict__ dw,
                           const float* __restrict__ cs_fin,
                           float* __restrict__ out) {
    int e = blockIdx.x * blockDim.x + threadIdx.x;
    if (e >= KC * DD) return;
    float na = 0.99f * embed_avg[e] + 0.01f * dw[e];
    float nw = na / cs_fin[e >> 6];
    out[EAOFF + e] = na;
    out[WOFF + e] = nw;
}

extern "C" void kernel_launch(void* const* d_in, const int* in_sizes, int n_in,
                              void* d_out, int out_size, void* d_ws, size_t ws_size,
                              hipStream_t stream) {
    (void)in_sizes; (void)n_in; (void)out_size; (void)ws_size;
    const float* x       = (const float*)d_in[0];
    const float* weight  = (const float*)d_in[1];
    const float* cluster = (const float*)d_in[2];
    const float* eavg    = (const float*)d_in[3];
    float* out = (float*)d_out;
    float* wsf = (float*)d_ws;

    float*    code_sq = wsf + WS_CODESQ;
    float*    counts  = wsf + WS_COUNTS;
    int*      rccnt   = (int*)(wsf + WS_RCCNT);
    int*      cursor  = (int*)(wsf + WS_CURSOR);
    int*      offs    = (int*)(wsf + WS_OFFS);
    float*    cs_fin  = wsf + WS_CSFIN;
    float*    dwbuf   = wsf + WS_DW;
    _Float16* whi     = (_Float16*)(wsf + WS_WHI);
    _Float16* wlo     = (_Float16*)(wsf + WS_WLO);
    int*      idxbuf  = (int*)(wsf + WS_IDX);
    int*      rclist  = (int*)(wsf + WS_RCLIST);
    int*      rowlist = (int*)(wsf + WS_ROWLIST);
    unsigned long long* packed = (unsigned long long*)(wsf + WS_PACKED);

    // init packed to all-ones (max u64); counts/rccnt zeroed in prep_kernel
    (void)hipMemsetAsync(packed, 0xFF, (size_t)NROWS * 8, stream);

    hipLaunchKernelGGL(prep_kernel, dim3(16), dim3(64), 0, stream,
                       weight, code_sq, whi, wlo, counts, rccnt);
    hipLaunchKernelGGL(vq_scan, dim3(1024), dim3(256), 0, stream,
                       x, code_sq, whi, wlo, out, counts, idxbuf, rccnt, rclist);
    hipLaunchKernelGGL(vq_recheck, dim3(2048), dim3(256), 0, stream,
                       x, weight, code_sq, packed, rccnt, rclist);
    hipLaunchKernelGGL(rc_finalize, dim3(256), dim3(256), 0, stream,
                       packed, rccnt, rclist, out, counts, idxbuf);
    hipLaunchKernelGGL(offsets_cs_kernel, dim3(1), dim3(1024), 0, stream,
                       counts, cluster, offs, cursor, out, cs_fin);
    hipLaunchKernelGGL(scatter_kernel, dim3(256), dim3(256), 0, stream,
                       idxbuf, offs, cursor, rowlist);
    hipLaunchKernelGGL(dw_q_kernel, dim3(1024), dim3(256), 0, stream,
                       x, weight, counts, offs, rowlist, out, dwbuf);
    hipLaunchKernelGGL(finalize_w, dim3(256), dim3(256), 0, stream,
                       eavg, dwbuf, cs_fin, out);
}